// Round 11
// baseline (581.929 us; speedup 1.0000x reference)
//
#include <hip/hip_runtime.h>
#include <hip/hip_bf16.h>
#include <stdint.h>

// Problem constants (fixed by setup_inputs)
#define NB    8
#define LQ    2048
#define LKK   2048
#define EMBD  1024

typedef __bf16 bf16_t;
typedef __bf16 bf16x8 __attribute__((ext_vector_type(8)));
typedef __bf16 bf16x4 __attribute__((ext_vector_type(4)));
typedef float  f32x4  __attribute__((ext_vector_type(4)));

// RNE float->bf16, branch-free (inputs are finite)
__device__ __forceinline__ bf16_t f2bf(float x) {
  union { float f; uint32_t u; } v; v.f = x;
  uint32_t r = v.u + 0x7fffu + ((v.u >> 16) & 1u);
  uint16_t h = (uint16_t)(r >> 16);
  return __builtin_bit_cast(bf16_t, h);
}

__device__ __forceinline__ float wred_sum(float v) {
#pragma unroll
  for (int o = 32; o; o >>= 1) v += __shfl_xor(v, o);
  return v;
}
__device__ __forceinline__ float wred_max(float v) {
#pragma unroll
  for (int o = 32; o; o >>= 1) v = fmaxf(v, __shfl_xor(v, o));
  return v;
}

// Bank-spreading XOR for the epilogue slab (64-col f32 rows).
// Differs across strided row-groups {R,R+4,R+8,R+12} (write side) AND
// consecutive rows {R..R+3} (read side): f = (row ^ (row>>2)) & 3.
__device__ __forceinline__ int slab_flip(int row) {
  return ((row ^ (row >> 2)) & 3) << 4;
}

// Shared epilogue: LDS-bounced, coalesced C-write, 4 passes (one per n-quarter,
// 64 contiguous cols each). slab = 256x64 f32 = 64 KiB (fits both variants).
// acc[m][n][j] holds C[bm+wm+m*16+(lane>>4)*4+j][bn + n*64 + wq*16 + (lane&15)]
template<int EPI>
__device__ __forceinline__ void gemm_epilogue(
    f32x4 (&acc)[8][4], char* smem, float* Cf, bf16_t* Cb,
    const float* bias, float scale, int N, long cbase,
    int bm, int bn, int wm, int wq, int tid, int lane)
{
  float* slab = (float*)smem;
  const int fr = lane & 15;
  const int g4 = (lane >> 4) << 2;
#pragma unroll
  for (int n = 0; n < 4; n++) {
    __syncthreads();                       // slab free (prev readers done)
#pragma unroll
    for (int m = 0; m < 8; m++) {
      const int rbase = wm + m * 16 + g4;
#pragma unroll
      for (int j = 0; j < 4; j++) {
        const int row = rbase + j;
        slab[row * 64 + ((wq * 16 + fr) ^ slab_flip(row))] = acc[m][n][j];
      }
    }
    __syncthreads();
    const int ncol = bn + n * 64;
    if constexpr (EPI == 3) {
      // f32 out: 8 passes x (32 rows x 16 thr x f32x4), 256 B segments
#pragma unroll
      for (int p = 0; p < 8; p++) {
        const int row = p * 32 + (tid >> 4);
        const int c4  = (tid & 15) * 4;
        f32x4 v = *(const f32x4*)&slab[row * 64 + (c4 ^ slab_flip(row))];
        const float4 bv = *(const float4*)&bias[ncol + c4];
        v[0] += bv.x; v[1] += bv.y; v[2] += bv.z; v[3] += bv.w;
        *(f32x4*)&Cf[cbase + (long)(bm + row) * N + ncol + c4] = v;
      }
    } else {
      // bf16 out: 4 passes x (64 rows x 8 thr x bf16x8), 128 B segments
#pragma unroll
      for (int p = 0; p < 4; p++) {
        const int row  = p * 64 + (tid >> 3);
        const int c8   = (tid & 7) * 8;
        const int flip = slab_flip(row);
        const f32x4 v0 = *(const f32x4*)&slab[row * 64 + (c8 ^ flip)];
        const f32x4 v1 = *(const f32x4*)&slab[row * 64 + ((c8 + 4) ^ flip)];
        const float vv[8] = {v0[0], v0[1], v0[2], v0[3], v1[0], v1[1], v1[2], v1[3]};
        bf16x8 o;
        if constexpr (EPI == 0) {
#pragma unroll
          for (int e = 0; e < 8; e++) o[e] = f2bf(vv[e] * scale);
        } else if constexpr (EPI == 1) {
#pragma unroll
          for (int e = 0; e < 8; e++) o[e] = f2bf(vv[e]);
        } else {   // EPI == 2: +bias, ReLU
          const float4 b0 = *(const float4*)&bias[ncol + c8];
          const float4 b1 = *(const float4*)&bias[ncol + c8 + 4];
          const float bb[8] = {b0.x, b0.y, b0.z, b0.w, b1.x, b1.y, b1.z, b1.w};
#pragma unroll
          for (int e = 0; e < 8; e++) o[e] = f2bf(fmaxf(vv[e] + bb[e], 0.0f));
        }
        *(bf16x8*)&Cb[cbase + (long)(bm + row) * N + ncol + c8] = o;
      }
    }
  }
}

// ---------------------------------------------------------------------------
// Batched NT GEMM, 256x256 tile, BK=64, 128 KiB LDS, 1 block/CU (CONTROL).
// R4-proven 2-phase: 8 waves 2Mx4N, dbuf, one plain __syncthreads per K-tile.
// LDS K-slice-major [buf][slice8][row256][8]: linear gload_lds dest (rule #21),
// conflict-free ds_read_b128. EPI: 0 bf16*scale; 1 bf16; 2 +bias ReLU; 3 +bias f32.
// ---------------------------------------------------------------------------
template<int EPI>
__global__ __launch_bounds__(512, 1)
void gemm_nt(const bf16_t* __restrict__ A, const bf16_t* __restrict__ B,
             float* __restrict__ Cf, bf16_t* __restrict__ Cb,
             const float* __restrict__ bias, float scale,
             int M, int N, int K, long sA, long sB, long sC)
{
  __shared__ __align__(16) char smem[131072];
  typedef bf16_t ldsbuf_t[8][256][8];            // 32 KiB per buffer
  ldsbuf_t* Abuf = (ldsbuf_t*)smem;
  ldsbuf_t* Bbuf = (ldsbuf_t*)(smem + 65536);

  const int tid  = threadIdx.x;
  const int lane = tid & 63;
  const int wave = tid >> 6;
  const int wq   = wave & 3;
  const int bz   = blockIdx.z;

  const bf16_t* Ab = A + (long)bz * sA;
  const bf16_t* Bb = B + (long)bz * sB;

  const int bm = blockIdx.x * 256;
  const int bn = blockIdx.y * 256;
  const int wm = (wave >> 2) * 128;

  f32x4 acc[8][4] = {};

  const int srow = tid & 255;
  const int sslc = tid >> 8;

  const int fr = lane & 15;
  const int fs = lane >> 4;

  auto STAGE = [&](int bufi, int kt) {
#pragma unroll
    for (int i = 0; i < 4; i++) {
      const int slc = sslc + 2 * i;
      __builtin_amdgcn_global_load_lds(
        (const __attribute__((address_space(1))) void*)(Ab + (long)(bm + srow) * K + kt + slc * 8),
        (__attribute__((address_space(3))) void*)((char*)&Abuf[bufi][0][0][0] + (tid + i * 512) * 16),
        16, 0, 0);
    }
#pragma unroll
    for (int i = 0; i < 4; i++) {
      const int slc = sslc + 2 * i;
      __builtin_amdgcn_global_load_lds(
        (const __attribute__((address_space(1))) void*)(Bb + (long)(bn + srow) * K + kt + slc * 8),
        (__attribute__((address_space(3))) void*)((char*)&Bbuf[bufi][0][0][0] + (tid + i * 512) * 16),
        16, 0, 0);
    }
  };

  auto COMPUTE = [&](int bufi) {
#pragma unroll
    for (int kk = 0; kk < 2; kk++) {
      bf16x8 af[8], bfg[4];
#pragma unroll
      for (int m = 0; m < 8; m++)
        af[m] = *(const bf16x8*)&Abuf[bufi][4 * kk + fs][wm + m * 16 + fr][0];
#pragma unroll
      for (int n = 0; n < 4; n++)
        bfg[n] = *(const bf16x8*)&Bbuf[bufi][4 * kk + fs][n * 64 + wq * 16 + fr][0];
#pragma unroll
      for (int m = 0; m < 8; m++)
#pragma unroll
        for (int n = 0; n < 4; n++)
          acc[m][n] = __builtin_amdgcn_mfma_f32_16x16x32_bf16(af[m], bfg[n], acc[m][n], 0, 0, 0);
    }
  };

  STAGE(0, 0);
  __syncthreads();
  int buf = 0;
  for (int kt = 64; kt < K; kt += 64) {
    STAGE(buf ^ 1, kt);
    COMPUTE(buf);
    __syncthreads();
    buf ^= 1;
  }
  COMPUTE(buf);

  gemm_epilogue<EPI>(acc, smem, Cf, Cb, bias, scale, N, (long)bz * sC,
                     bm, bn, wm, wq, tid, lane);
}

// ---------------------------------------------------------------------------
// EXPERIMENT: same structure, BK=32 -> 64 KiB LDS -> 2 blocks/CU
// (__launch_bounds__(512,2)). Twice the barriers, but a co-resident block
// hides each drain (m114 block-level overlap; m103's high-occupancy regime).
// ---------------------------------------------------------------------------
template<int EPI>
__global__ __launch_bounds__(512, 2)
void gemm_nt32(const bf16_t* __restrict__ A, const bf16_t* __restrict__ B,
               float* __restrict__ Cf, bf16_t* __restrict__ Cb,
               const float* __restrict__ bias, float scale,
               int M, int N, int K, long sA, long sB, long sC)
{
  __shared__ __align__(16) char smem[65536];
  typedef bf16_t ldsbuf_t[4][256][8];            // 16 KiB per buffer
  ldsbuf_t* Abuf = (ldsbuf_t*)smem;              // [0..1]
  ldsbuf_t* Bbuf = (ldsbuf_t*)(smem + 32768);    // [0..1]

  const int tid  = threadIdx.x;
  const int lane = tid & 63;
  const int wave = tid >> 6;
  const int wq   = wave & 3;
  const int bz   = blockIdx.z;

  const bf16_t* Ab = A + (long)bz * sA;
  const bf16_t* Bb = B + (long)bz * sB;

  const int bm = blockIdx.x * 256;
  const int bn = blockIdx.y * 256;
  const int wm = (wave >> 2) * 128;

  f32x4 acc[8][4] = {};

  const int srow = tid & 255;
  const int sslc = tid >> 8;          // 0 or 1

  const int fr = lane & 15;
  const int fs = lane >> 4;

  // A half-tile (256x32) = 1024 slots x 16 B; 512 thr x 2 issues each of A,B.
  auto STAGE = [&](int bufi, int kt) {
#pragma unroll
    for (int i = 0; i < 2; i++) {
      const int slc = sslc + 2 * i;
      __builtin_amdgcn_global_load_lds(
        (const __attribute__((address_space(1))) void*)(Ab + (long)(bm + srow) * K + kt + slc * 8),
        (__attribute__((address_space(3))) void*)((char*)&Abuf[bufi][0][0][0] + (tid + i * 512) * 16),
        16, 0, 0);
      __builtin_amdgcn_global_load_lds(
        (const __attribute__((address_space(1))) void*)(Bb + (long)(bn + srow) * K + kt + slc * 8),
        (__attribute__((address_space(3))) void*)((char*)&Bbuf[bufi][0][0][0] + (tid + i * 512) * 16),
        16, 0, 0);
    }
  };

  auto COMPUTE = [&](int bufi) {
    bf16x8 af[8], bfg[4];
#pragma unroll
    for (int m = 0; m < 8; m++)
      af[m] = *(const bf16x8*)&Abuf[bufi][fs][wm + m * 16 + fr][0];
#pragma unroll
    for (int n = 0; n < 4; n++)
      bfg[n] = *(const bf16x8*)&Bbuf[bufi][fs][n * 64 + wq * 16 + fr][0];
#pragma unroll
    for (int m = 0; m < 8; m++)
#pragma unroll
      for (int n = 0; n < 4; n++)
        acc[m][n] = __builtin_amdgcn_mfma_f32_16x16x32_bf16(af[m], bfg[n], acc[m][n], 0, 0, 0);
  };

  STAGE(0, 0);
  __syncthreads();
  int buf = 0;
  for (int kt = 32; kt < K; kt += 32) {
    STAGE(buf ^ 1, kt);
    COMPUTE(buf);
    __syncthreads();
    buf ^= 1;
  }
  COMPUTE(buf);

  gemm_epilogue<EPI>(acc, smem, Cf, Cb, bias, scale, N, (long)bz * sC,
                     bm, bn, wm, wq, tid, lane);
}

// ---------------------------------------------------------------------------
// Row softmax over S [(nb)*LQ][LKK] bf16 (already scaled) -> P bf16, in-place
// capable. km/qm pointers pre-offset to the batch range.
// ---------------------------------------------------------------------------
__global__ __launch_bounds__(256)
void softmax_kernel(const bf16_t* __restrict__ S, bf16_t* __restrict__ P,
                    const float* __restrict__ km, const float* __restrict__ qm)
{
  __shared__ float red[8];
  const int r = blockIdx.x;
  const int b = r >> 11;              // local batch index (r / LQ)
  const int t = threadIdx.x;
  const bf16_t* row = S + (long)r * LKK;

  const bf16x8 sv = *(const bf16x8*)(row + t * 8);
  const float4 k0 = ((const float4*)(km + (long)b * LKK))[2 * t];
  const float4 k1 = ((const float4*)(km + (long)b * LKK))[2 * t + 1];
  const float kmv[8] = {k0.x, k0.y, k0.z, k0.w, k1.x, k1.y, k1.z, k1.w};

  float v[8];
  float mx = -3.4e38f;
#pragma unroll
  for (int i = 0; i < 8; i++) {
    float s = (float)sv[i];
    s = (kmv[i] == 0.0f) ? -4294967295.0f : s;   // NEG_INF
    v[i] = s;
    mx = fmaxf(mx, s);
  }
  mx = wred_max(mx);
  if ((t & 63) == 0) red[t >> 6] = mx;
  __syncthreads();
  mx = fmaxf(fmaxf(red[0], red[1]), fmaxf(red[2], red[3]));

  float sum = 0.0f;
#pragma unroll
  for (int i = 0; i < 8; i++) {
    const float e = __expf(v[i] - mx);
    v[i] = e;
    sum += e;
  }
  sum = wred_sum(sum);
  if ((t & 63) == 0) red[4 + (t >> 6)] = sum;
  __syncthreads();
  sum = red[4] + red[5] + red[6] + red[7];

  const float rs = qm[r] / sum;
  bf16x8 o;
#pragma unroll
  for (int i = 0; i < 8; i++) o[i] = f2bf(v[i] * rs);
  *(bf16x8*)(P + (long)r * LKK + t * 8) = o;
}

// ---------------------------------------------------------------------------
// Fused residual + LayerNorm: Y = LN(X + R)*w + b  (rows of EMBD)
// MODE bit0: X bf16 (else f32); bit1: R bf16; bit2: Y bf16 (else f32).
// ---------------------------------------------------------------------------
template<int MODE>
__global__ __launch_bounds__(256)
void ln_kernel(const void* __restrict__ Xv, const void* __restrict__ Rv,
               const float* __restrict__ w, const float* __restrict__ bp,
               void* __restrict__ Yv)
{
  __shared__ float red[8];
  const long r = blockIdx.x;
  const int t = threadIdx.x;

  float x0, x1, x2, x3;
  if constexpr (MODE & 1) {
    const bf16x4 xv = ((const bf16x4*)((const bf16_t*)Xv + r * EMBD))[t];
    x0 = (float)xv[0]; x1 = (float)xv[1]; x2 = (float)xv[2]; x3 = (float)xv[3];
  } else {
    const float4 xv = ((const float4*)((const float*)Xv + r * EMBD))[t];
    x0 = xv.x; x1 = xv.y; x2 = xv.z; x3 = xv.w;
  }
  float r0, r1, r2, r3;
  if constexpr (MODE & 2) {
    const bf16x4 rv = ((const bf16x4*)((const bf16_t*)Rv + r * EMBD))[t];
    r0 = (float)rv[0]; r1 = (float)rv[1]; r2 = (float)rv[2]; r3 = (float)rv[3];
  } else {
    const float4 rv = ((const float4*)((const float*)Rv + r * EMBD))[t];
    r0 = rv.x; r1 = rv.y; r2 = rv.z; r3 = rv.w;
  }
  const float s0 = x0 + r0, s1 = x1 + r1, s2 = x2 + r2, s3 = x3 + r3;

  float sum = wred_sum(s0 + s1 + s2 + s3);
  if ((t & 63) == 0) red[t >> 6] = sum;
  __syncthreads();
  const float mu = (red[0] + red[1] + red[2] + red[3]) * (1.0f / EMBD);

  const float d0 = s0 - mu, d1 = s1 - mu, d2 = s2 - mu, d3 = s3 - mu;
  float sq = wred_sum(d0 * d0 + d1 * d1 + d2 * d2 + d3 * d3);
  if ((t & 63) == 0) red[4 + (t >> 6)] = sq;
  __syncthreads();
  const float var = (red[4] + red[5] + red[6] + red[7]) * (1.0f / EMBD);
  const float rstd = rsqrtf(var + 1e-5f);

  const float4 wv = ((const float4*)w)[t];
  const float4 bv = ((const float4*)bp)[t];
  const float y0 = d0 * rstd * wv.x + bv.x;
  const float y1 = d1 * rstd * wv.y + bv.y;
  const float y2 = d2 * rstd * wv.z + bv.z;
  const float y3 = d3 * rstd * wv.w + bv.w;

  if constexpr (MODE & 4) {
    bf16x4 o; o[0] = f2bf(y0); o[1] = f2bf(y1); o[2] = f2bf(y2); o[3] = f2bf(y3);
    ((bf16x4*)((bf16_t*)Yv + r * EMBD))[t] = o;
  } else {
    ((float4*)((float*)Yv + r * EMBD))[t] = make_float4(y0, y1, y2, y3);
  }
}

// flat f32 -> bf16 (vectorized, grid-stride)
__global__ void cvt_kernel(const float* __restrict__ in, bf16_t* __restrict__ out, long n4)
{
  long i = (long)blockIdx.x * 256 + threadIdx.x;
  const long stride = (long)gridDim.x * 256;
  for (; i < n4; i += stride) {
    const float4 v = ((const float4*)in)[i];
    bf16x4 o; o[0] = f2bf(v.x); o[1] = f2bf(v.y); o[2] = f2bf(v.z); o[3] = f2bf(v.w);
    ((bf16x4*)out)[i] = o;
  }
}

// batched [z][rows][cols] f32 -> transposed bf16 [z][cols][rows] AND straight
// bf16 copy [z][rows][cols] in one read pass.
__global__ __launch_bounds__(256)
void transpose_cvt(const float* __restrict__ in, bf16_t* __restrict__ outT,
                   bf16_t* __restrict__ outS, int rows, int cols)
{
  __shared__ bf16_t tile[32][33];
  const long zb = (long)blockIdx.z * rows * cols;
  const int cb = blockIdx.x * 32;      // col coord
  const int rb = blockIdx.y * 32;      // row coord
  const int tx = threadIdx.x & 31;
  const int ty = threadIdx.x >> 5;     // 0..7
#pragma unroll
  for (int i = 0; i < 4; i++) {
    const int rr = ty + i * 8;
    const bf16_t v = f2bf(in[zb + (long)(rb + rr) * cols + cb + tx]);
    tile[rr][tx] = v;
    if (outS != nullptr) outS[zb + (long)(rb + rr) * cols + cb + tx] = v;
  }
  __syncthreads();
#pragma unroll
  for (int i = 0; i < 4; i++) {
    const int cc = ty + i * 8;
    outT[zb + (long)(cb + cc) * rows + rb + tx] = tile[tx][cc];
  }
}

// ---------------------------------------------------------------------------
extern "C" void kernel_launch(void* const* d_in, const int* in_sizes, int n_in,
                              void* d_out, int out_size, void* d_ws, size_t ws_size,
                              hipStream_t stream)
{
  const float* q    = (const float*)d_in[0];
  const float* k    = (const float*)d_in[1];
  const float* qm   = (const float*)d_in[2];
  const float* km   = (const float*)d_in[3];
  const float* lnw  = (const float*)d_in[4];
  const float* lnb  = (const float*)d_in[5];
  const float* ln2w = (const float*)d_in[6];
  const float* ln2b = (const float*)d_in[7];
  const float* W1   = (const float*)d_in[8];
  const float* b1   = (const float*)d_in[9];
  const float* W2   = (const float*)d_in[10];
  const float* b2   = (const float*)d_in[11];

  char* ws = (char*)d_ws;
  char* ob = (char*)d_out;
  const float scale = 0.03125f;             // 1/(sqrt(1024)+1e-8)
  const long MB = 1L << 20;
  const long QE = (long)LQ * EMBD;          // 2M elems per batch (Q-shaped)
  const long SS = (long)LQ * LKK;           // 4M elems per batch (S-shaped)

  if (ws_size >= 100 * MB) {
    // ================= Tier A: fully batched (z=8) =================
    bf16_t* Qb   = (bf16_t*)ws;
    bf16_t* attn = (bf16_t*)ws;                  // overlays Qb (dead after QK)
    bf16_t* Kb   = (bf16_t*)(ws + 32 * MB);
    bf16_t* h    = (bf16_t*)(ws + 32 * MB);      // overlays Kb (dead after QK)
    bf16_t* Kt   = (bf16_t*)(ws + 64 * MB);
    bf16_t* W1b  = (bf16_t*)(ws + 96 * MB);
    bf16_t* W2b  = (bf16_t*)(ws + 98 * MB);
    bf16_t* Sb   = (bf16_t*)ob;                  // 64 MiB, whole d_out
    float*  y    = (float*)ob;

    cvt_kernel<<<1024, 256, 0, stream>>>(W1, W1b, (long)EMBD * EMBD / 4);
    cvt_kernel<<<1024, 256, 0, stream>>>(W2, W2b, (long)EMBD * EMBD / 4);
    cvt_kernel<<<4096, 256, 0, stream>>>(q, Qb, (long)NB * QE / 4);
    transpose_cvt<<<dim3(EMBD / 32, LKK / 32, NB), 256, 0, stream>>>(k, Kt, Kb, LKK, EMBD);

    // S = (Q K^T)/32   [BK32, 2 blocks/CU]
    gemm_nt32<0><<<dim3(LQ / 256, LKK / 256, NB), 512, 0, stream>>>(
        Qb, Kb, nullptr, Sb, nullptr, scale, LQ, LKK, EMBD, QE, QE, SS);
    // P = qmask * softmax(mask(S))   (in-place)
    softmax_kernel<<<NB * LQ, 256, 0, stream>>>(Sb, Sb, km, qm);
    // attn = P @ K    [BK32]
    gemm_nt32<1><<<dim3(LQ / 256, EMBD / 256, NB), 512, 0, stream>>>(
        Sb, Kt, nullptr, attn, nullptr, 0.0f, LQ, EMBD, LKK, SS, (long)EMBD * LKK, QE);
    // x = LN(attn + q) in-place
    ln_kernel<5><<<NB * LQ, 256, 0, stream>>>(attn, q, lnw, lnb, attn);
    // FFN1: BK32 (A/B treatment)
    gemm_nt32<2><<<dim3(NB * LQ / 256, EMBD / 256, 1), 512, 0, stream>>>(
        attn, W1b, nullptr, h, b1, 0.0f, NB * LQ, EMBD, EMBD, 0, 0, 0);
    // FFN2: BK64 (same-shape CONTROL)
    gemm_nt<3><<<dim3(NB * LQ / 256, EMBD / 256, 1), 512, 0, stream>>>(
        h, W2b, y, nullptr, b2, 0.0f, NB * LQ, EMBD, EMBD, 0, 0, 0);
    // out = LN(y + x) in-place
    ln_kernel<2><<<NB * LQ, 256, 0, stream>>>(y, attn, ln2w, ln2b, y);

  } else if (ws_size >= 52 * MB) {
    // ================= Tier B: two half-batches (z=4) =================
    bf16_t* attn = (bf16_t*)ws;
    bf16_t* W1b  = (bf16_t*)(ws + 32 * MB);
    bf16_t* W2b  = (bf16_t*)(ws + 34 * MB);
    bf16_t* Kth  = (bf16_t*)(ws + 36 * MB);
    bf16_t* h    = (bf16_t*)(ws + 36 * MB);      // overlays Kth (dead after PV)
    bf16_t* Sb   = (bf16_t*)ob;
    bf16_t* Qbh  = (bf16_t*)(ob + 32 * MB);
    bf16_t* Kbh  = (bf16_t*)(ob + 48 * MB);
    float*  y    = (float*)ob;

    cvt_kernel<<<1024, 256, 0, stream>>>(W1, W1b, (long)EMBD * EMBD / 4);
    cvt_kernel<<<1024, 256, 0, stream>>>(W2, W2b, (long)EMBD * EMBD / 4);

    for (int it = 0; it < 2; it++) {
      const int bo = it * 4;
      const float* qh = q + bo * QE;
      const float* kh = k + bo * QE;
      cvt_kernel<<<2048, 256, 0, stream>>>(qh, Qbh, 4 * QE / 4);
      transpose_cvt<<<dim3(EMBD / 32, LKK / 32, 4), 256, 0, stream>>>(kh, Kth, Kbh, LKK, EMBD);

      gemm_nt32<0><<<dim3(LQ / 256, LKK / 256, 4), 512, 0, stream>>>(
          Qbh, Kbh, nullptr, Sb, nullptr, scale, LQ, LKK, EMBD, QE, QE, SS);
      softmax_kernel<<<4 * LQ, 256, 0, stream>>>(Sb, Sb, km + bo * LKK, qm + bo * LQ);
      gemm_nt32<1><<<dim3(LQ / 256, EMBD / 256, 4), 512, 0, stream>>>(
          Sb, Kth, nullptr, attn + bo * QE, nullptr, 0.0f, LQ, EMBD, LKK,
          SS, (long)EMBD * LKK, QE);
    }
    ln_kernel<5><<<NB * LQ, 256, 0, stream>>>(attn, q, lnw, lnb, attn);
    for (int c = 0; c < 2; c++) {
      bf16_t* xc = attn + (long)c * 8192 * EMBD;
      float*  yc = y + (long)c * 8192 * EMBD;
      gemm_nt32<2><<<dim3(8192 / 256, EMBD / 256, 1), 512, 0, stream>>>(
          xc, W1b, nullptr, h, b1, 0.0f, 8192, EMBD, EMBD, 0, 0, 0);
      gemm_nt<3><<<dim3(8192 / 256, EMBD / 256, 1), 512, 0, stream>>>(
          h, W2b, yc, nullptr, b2, 0.0f, 8192, EMBD, EMBD, 0, 0, 0);
    }
    ln_kernel<2><<<NB * LQ, 256, 0, stream>>>(y, attn, ln2w, ln2b, y);

  } else {
    // ================= Tier C: per-batch 44 MiB fallback =================
    if (ws_size < 44 * MB) return;
    bf16_t* attn = (bf16_t*)ws;
    bf16_t* W1b  = (bf16_t*)(ws + 32 * MB);
    bf16_t* W2b  = (bf16_t*)(ws + 34 * MB);
    bf16_t* h    = (bf16_t*)(ws + 36 * MB);
    bf16_t* Sb   = (bf16_t*)(ob);
    bf16_t* Pb   = (bf16_t*)(ob + 8 * MB);
    bf16_t* Qbb  = (bf16_t*)(ob + 16 * MB);
    bf16_t* Kbb  = (bf16_t*)(ob + 20 * MB);
    bf16_t* Ktb  = (bf16_t*)(ob + 24 * MB);

    cvt_kernel<<<1024, 256, 0, stream>>>(W1, W1b, (long)EMBD * EMBD / 4);
    cvt_kernel<<<1024, 256, 0, stream>>>(W2, W2b, (long)EMBD * EMBD / 4);

    for (int b = 0; b < NB; b++) {
      const float* qb = q + b * QE;
      const float* kb = k + b * QE;
      cvt_kernel<<<2048, 256, 0, stream>>>(qb, Qbb, QE / 4);
      transpose_cvt<<<dim3(EMBD / 32, LKK / 32, 1), 256, 0, stream>>>(kb, Ktb, Kbb, LKK, EMBD);

      gemm_nt32<0><<<dim3(LQ / 256, LKK / 256, 1), 512, 0, stream>>>(
          Qbb, Kbb, nullptr, Sb, nullptr, scale, LQ, LKK, EMBD, 0, 0, 0);
      softmax_kernel<<<LQ, 256, 0, stream>>>(Sb, Pb, km + (long)b * LKK, qm + (long)b * LQ);
      gemm_nt32<1><<<dim3(LQ / 256, EMBD / 256, 1), 512, 0, stream>>>(
          Pb, Ktb, nullptr, attn + b * QE, nullptr, 0.0f, LQ, EMBD, LKK, 0, 0, 0);
    }
    ln_kernel<5><<<NB * LQ, 256, 0, stream>>>(attn, q, lnw, lnb, attn);
    for (int c = 0; c < 4; c++) {
      bf16_t* xc = attn + (long)c * 4096 * EMBD;
      float*  yc = (float*)d_out + (long)c * 4096 * EMBD;
      gemm_nt32<2><<<dim3(4096 / 256, EMBD / 256, 1), 512, 0, stream>>>(
          xc, W1b, nullptr, h, b1, 0.0f, 4096, EMBD, EMBD, 0, 0, 0);
      gemm_nt<3><<<dim3(4096 / 256, EMBD / 256, 1), 512, 0, stream>>>(
          h, W2b, yc, nullptr, b2, 0.0f, 4096, EMBD, EMBD, 0, 0, 0);
      ln_kernel<2><<<4096, 256, 0, stream>>>(yc, xc, ln2w, ln2b, yc);
    }
  }
}

// Round 12
// 447.755 us; speedup vs baseline: 1.2997x; 1.2997x over previous
//
#include <hip/hip_runtime.h>
#include <hip/hip_bf16.h>
#include <stdint.h>

// Problem constants (fixed by setup_inputs)
#define NB    8
#define LQ    2048
#define LKK   2048
#define EMBD  1024

typedef __bf16 bf16_t;
typedef __bf16 bf16x8 __attribute__((ext_vector_type(8)));
typedef __bf16 bf16x4 __attribute__((ext_vector_type(4)));
typedef float  f32x4  __attribute__((ext_vector_type(4)));

// RNE float->bf16, branch-free (inputs are finite)
__device__ __forceinline__ bf16_t f2bf(float x) {
  union { float f; uint32_t u; } v; v.f = x;
  uint32_t r = v.u + 0x7fffu + ((v.u >> 16) & 1u);
  uint16_t h = (uint16_t)(r >> 16);
  return __builtin_bit_cast(bf16_t, h);
}

__device__ __forceinline__ float wred_sum(float v) {
#pragma unroll
  for (int o = 32; o; o >>= 1) v += __shfl_xor(v, o);
  return v;
}
__device__ __forceinline__ float wred_max(float v) {
#pragma unroll
  for (int o = 32; o; o >>= 1) v = fmaxf(v, __shfl_xor(v, o));
  return v;
}

// Shared epilogue (R10-proven, 113us QK): LDS-bounced coalesced C-write.
// acc[m][n][j] holds C[bm+wm+m*16+(lane>>4)*4+j][bn + n*64 + wq*16 + (lane&15)]
// slab = 256x128 f32 (128 KiB); bit4-XOR on (row>>2)&1 keeps write aliasing
// at free 2-way. Two col-halves of 128; 256 B store segments.
template<int EPI>
__device__ __forceinline__ void gemm_epilogue(
    f32x4 (&acc)[8][4], char* smem, float* Cf, bf16_t* Cb,
    const float* bias, float scale, int N, long cbase,
    int bm, int bn, int wm, int wq, int tid, int lane)
{
  float* slab = (float*)smem;
  const int fr = lane & 15;
#pragma unroll
  for (int h = 0; h < 2; h++) {
    __syncthreads();
#pragma unroll
    for (int nn = 0; nn < 2; nn++) {
      const int n = 2 * h + nn;
      const int colb = nn * 64 + wq * 16 + fr;
#pragma unroll
      for (int m = 0; m < 8; m++) {
        const int rbase = wm + m * 16 + ((lane >> 4) << 2);
#pragma unroll
        for (int j = 0; j < 4; j++) {
          const int row = rbase + j;
          slab[row * 128 + (colb ^ (((row >> 2) & 1) << 4))] = acc[m][n][j];
        }
      }
    }
    __syncthreads();
    const int hcol = bn + h * 128;
    if constexpr (EPI == 3) {
#pragma unroll
      for (int p = 0; p < 16; p++) {
        const int row = p * 16 + (tid >> 5);
        const int c4  = (tid & 31) * 4;
        f32x4 v = *(const f32x4*)&slab[row * 128 + (c4 ^ (((row >> 2) & 1) << 4))];
        const float4 bv = *(const float4*)&bias[hcol + c4];
        v[0] += bv.x; v[1] += bv.y; v[2] += bv.z; v[3] += bv.w;
        *(f32x4*)&Cf[cbase + (long)(bm + row) * N + hcol + c4] = v;
      }
    } else {
#pragma unroll
      for (int p = 0; p < 8; p++) {
        const int row  = p * 32 + (tid >> 4);
        const int c8   = (tid & 15) * 8;
        const int flip = ((row >> 2) & 1) << 4;
        const f32x4 v0 = *(const f32x4*)&slab[row * 128 + (c8 ^ flip)];
        const f32x4 v1 = *(const f32x4*)&slab[row * 128 + ((c8 + 4) ^ flip)];
        const float vv[8] = {v0[0], v0[1], v0[2], v0[3], v1[0], v1[1], v1[2], v1[3]};
        bf16x8 o;
        if constexpr (EPI == 0) {
#pragma unroll
          for (int e = 0; e < 8; e++) o[e] = f2bf(vv[e] * scale);
        } else if constexpr (EPI == 1) {
#pragma unroll
          for (int e = 0; e < 8; e++) o[e] = f2bf(vv[e]);
        } else {
          const float4 b0 = *(const float4*)&bias[hcol + c8];
          const float4 b1 = *(const float4*)&bias[hcol + c8 + 4];
          const float bb[8] = {b0.x, b0.y, b0.z, b0.w, b1.x, b1.y, b1.z, b1.w};
#pragma unroll
          for (int e = 0; e < 8; e++) o[e] = f2bf(fmaxf(vv[e] + bb[e], 0.0f));
        }
        *(bf16x8*)&Cb[cbase + (long)(bm + row) * N + hcol + c8] = o;
      }
    }
  }
}

// ---------------------------------------------------------------------------
// Batched NT GEMM, 256x256, BK=64, 2-phase (R10-proven: 113us @ QK shape).
// 8 waves 2Mx4N, dbuf 128 KiB LDS, one plain __syncthreads per K-tile.
// LDS K-slice-major [buf][slice8][row256][8]: linear gload_lds dest (rule
// #21), conflict-free ds_read_b128. No XCD swizzle (L3-resident regime).
// EPI: 0 bf16*scale; 1 bf16; 2 +bias ReLU bf16; 3 +bias f32.
// ---------------------------------------------------------------------------
template<int EPI>
__global__ __launch_bounds__(512, 1)
void gemm_nt(const bf16_t* __restrict__ A, const bf16_t* __restrict__ B,
             float* __restrict__ Cf, bf16_t* __restrict__ Cb,
             const float* __restrict__ bias, float scale,
             int M, int N, int K, long sA, long sB, long sC)
{
  __shared__ __align__(16) char smem[131072];
  typedef bf16_t ldsbuf_t[8][256][8];            // 32 KiB per buffer
  ldsbuf_t* Abuf = (ldsbuf_t*)smem;
  ldsbuf_t* Bbuf = (ldsbuf_t*)(smem + 65536);

  const int tid  = threadIdx.x;
  const int lane = tid & 63;
  const int wave = tid >> 6;
  const int wq   = wave & 3;
  const int bz   = blockIdx.z;

  const bf16_t* Ab = A + (long)bz * sA;
  const bf16_t* Bb = B + (long)bz * sB;

  const int bm = blockIdx.x * 256;
  const int bn = blockIdx.y * 256;
  const int wm = (wave >> 2) * 128;

  f32x4 acc[8][4] = {};

  const int srow = tid & 255;
  const int sslc = tid >> 8;

  const int fr = lane & 15;
  const int fs = lane >> 4;

  auto STAGE = [&](int bufi, int kt) {
#pragma unroll
    for (int i = 0; i < 4; i++) {
      const int slc = sslc + 2 * i;
      __builtin_amdgcn_global_load_lds(
        (const __attribute__((address_space(1))) void*)(Ab + (long)(bm + srow) * K + kt + slc * 8),
        (__attribute__((address_space(3))) void*)((char*)&Abuf[bufi][0][0][0] + (tid + i * 512) * 16),
        16, 0, 0);
    }
#pragma unroll
    for (int i = 0; i < 4; i++) {
      const int slc = sslc + 2 * i;
      __builtin_amdgcn_global_load_lds(
        (const __attribute__((address_space(1))) void*)(Bb + (long)(bn + srow) * K + kt + slc * 8),
        (__attribute__((address_space(3))) void*)((char*)&Bbuf[bufi][0][0][0] + (tid + i * 512) * 16),
        16, 0, 0);
    }
  };

  auto COMPUTE = [&](int bufi) {
#pragma unroll
    for (int kk = 0; kk < 2; kk++) {
      bf16x8 af[8], bfg[4];
#pragma unroll
      for (int m = 0; m < 8; m++)
        af[m] = *(const bf16x8*)&Abuf[bufi][4 * kk + fs][wm + m * 16 + fr][0];
#pragma unroll
      for (int n = 0; n < 4; n++)
        bfg[n] = *(const bf16x8*)&Bbuf[bufi][4 * kk + fs][n * 64 + wq * 16 + fr][0];
#pragma unroll
      for (int m = 0; m < 8; m++)
#pragma unroll
        for (int n = 0; n < 4; n++)
          acc[m][n] = __builtin_amdgcn_mfma_f32_16x16x32_bf16(af[m], bfg[n], acc[m][n], 0, 0, 0);
    }
  };

  STAGE(0, 0);
  __syncthreads();
  int buf = 0;
  for (int kt = 64; kt < K; kt += 64) {
    STAGE(buf ^ 1, kt);
    COMPUTE(buf);
    __syncthreads();
    buf ^= 1;
  }
  COMPUTE(buf);

  gemm_epilogue<EPI>(acc, smem, Cf, Cb, bias, scale, N, (long)bz * sC,
                     bm, bn, wm, wq, tid, lane);
}

// ---------------------------------------------------------------------------
// EXPERIMENT (on PV this round — a ~113us dispatch, so the verdict is
// visible in top-5): R9's race-validated counted-vmcnt 4-phase pipeline
// (refcheck-passed on FFN1 in R9), with B-reads remapped to the
// n*64+wq*16 mapping and the R10 coalesced epilogue.
// Gating ledger (chunk = 2 loads/wave): prologue c0..c3 = 8, vmcnt(4),
// barrier. p1-end vmcnt(4) retires c2,c3(t); p3-end vmcnt(4) retires
// c0,c1(t+1). In-flight floats 4-8, never 0 mid-loop (T4). Tail drains 0
// at p1-end. Every gate precedes a barrier that precedes the consuming
// ds_read. No sched_barrier(0) (m141).
// ---------------------------------------------------------------------------
template<int EPI>
__global__ __launch_bounds__(512, 1)
void gemm_nt8(const bf16_t* __restrict__ A, const bf16_t* __restrict__ B,
              float* __restrict__ Cf, bf16_t* __restrict__ Cb,
              const float* __restrict__ bias, float scale,
              int M, int N, int K, long sA, long sB, long sC)
{
  __shared__ __align__(16) char smem[131072];
  typedef bf16_t ldsbuf_t[8][256][8];
  ldsbuf_t* Abuf = (ldsbuf_t*)smem;
  ldsbuf_t* Bbuf = (ldsbuf_t*)(smem + 65536);

  const int tid  = threadIdx.x;
  const int lane = tid & 63;
  const int wave = tid >> 6;
  const int wq   = wave & 3;
  const int bz   = blockIdx.z;

  const bf16_t* Ab = A + (long)bz * sA;
  const bf16_t* Bb = B + (long)bz * sB;

  const int bm = blockIdx.x * 256;
  const int bn = blockIdx.y * 256;
  const int wm = (wave >> 2) * 128;

  f32x4 acc[8][4] = {};

  const int fr = lane & 15;
  const int fs = lane >> 4;

  // chunk c: 0 = A slices0-3, 1 = B slices0-3, 2 = A slices4-7, 3 = B slices4-7
  auto STAGE_CHUNK = [&](int bufi, int kt, int c) {
    const bf16_t* src = (c & 1) ? Bb : Ab;
    const int base    = (c & 1) ? bn : bm;
    char* dst = ((c & 1) ? (char*)&Bbuf[bufi][0][0][0] : (char*)&Abuf[bufi][0][0][0])
                + (c >> 1) * 16384;
    const int kofs = kt + (c >> 1) * 32;
#pragma unroll
    for (int i = 0; i < 2; i++) {
      const int slot = tid + i * 512;
      const int slc  = slot >> 8;
      const int row  = slot & 255;
      __builtin_amdgcn_global_load_lds(
        (const __attribute__((address_space(1))) void*)(src + (long)(base + row) * K + kofs + slc * 8),
        (__attribute__((address_space(3))) void*)(dst + slot * 16), 16, 0, 0);
    }
  };

  auto MFMA16 = [&](bf16x8 (&af)[8], bf16x8 bx, bf16x8 by, int n0, int n1) {
    __builtin_amdgcn_s_setprio(1);
#pragma unroll
    for (int m = 0; m < 8; m++)
      acc[m][n0] = __builtin_amdgcn_mfma_f32_16x16x32_bf16(af[m], bx, acc[m][n0], 0, 0, 0);
#pragma unroll
    for (int m = 0; m < 8; m++)
      acc[m][n1] = __builtin_amdgcn_mfma_f32_16x16x32_bf16(af[m], by, acc[m][n1], 0, 0, 0);
    __builtin_amdgcn_s_setprio(0);
  };

  const int nt = K >> 6;

  STAGE_CHUNK(0, 0, 0); STAGE_CHUNK(0, 0, 1);
  STAGE_CHUNK(0, 0, 2); STAGE_CHUNK(0, 0, 3);
  asm volatile("s_waitcnt vmcnt(4)" ::: "memory");
  __builtin_amdgcn_s_barrier();

  for (int t = 0; t < nt; ++t) {
    const int cur = t & 1, nxt = cur ^ 1;
    const bool pf = (t + 1 < nt);
    const int ktn = (t + 1) << 6;
    bf16x8 af[8], b0, b1;

    // phase 0: kk=0, n{0,1}; stage c0(t+1). [c0,c1(t) gated at t-1.p3]
#pragma unroll
    for (int m = 0; m < 8; m++) af[m] = *(const bf16x8*)&Abuf[cur][fs][wm + m * 16 + fr][0];
    b0 = *(const bf16x8*)&Bbuf[cur][fs][wq * 16 + fr][0];
    b1 = *(const bf16x8*)&Bbuf[cur][fs][64 + wq * 16 + fr][0];
    if (pf) STAGE_CHUNK(nxt, ktn, 0);
    __builtin_amdgcn_s_barrier();
    asm volatile("s_waitcnt lgkmcnt(0)" ::: "memory");
    MFMA16(af, b0, b1, 0, 1);
    __builtin_amdgcn_s_barrier();

    // phase 1: kk=0, n{2,3}; stage c1(t+1); GATE c2,c3(t) at end.
    b0 = *(const bf16x8*)&Bbuf[cur][fs][128 + wq * 16 + fr][0];
    b1 = *(const bf16x8*)&Bbuf[cur][fs][192 + wq * 16 + fr][0];
    if (pf) STAGE_CHUNK(nxt, ktn, 1);
    __builtin_amdgcn_s_barrier();
    asm volatile("s_waitcnt lgkmcnt(0)" ::: "memory");
    MFMA16(af, b0, b1, 2, 3);
    if (pf) asm volatile("s_waitcnt vmcnt(4)" ::: "memory");
    else    asm volatile("s_waitcnt vmcnt(0)" ::: "memory");
    __builtin_amdgcn_s_barrier();

    // phase 2: kk=1, n{0,1}; stage c2(t+1).
#pragma unroll
    for (int m = 0; m < 8; m++) af[m] = *(const bf16x8*)&Abuf[cur][4 + fs][wm + m * 16 + fr][0];
    b0 = *(const bf16x8*)&Bbuf[cur][4 + fs][wq * 16 + fr][0];
    b1 = *(const bf16x8*)&Bbuf[cur][4 + fs][64 + wq * 16 + fr][0];
    if (pf) STAGE_CHUNK(nxt, ktn, 2);
    __builtin_amdgcn_s_barrier();
    asm volatile("s_waitcnt lgkmcnt(0)" ::: "memory");
    MFMA16(af, b0, b1, 0, 1);
    __builtin_amdgcn_s_barrier();

    // phase 3: kk=1, n{2,3}; stage c3(t+1); GATE c0,c1(t+1) at end.
    b0 = *(const bf16x8*)&Bbuf[cur][4 + fs][128 + wq * 16 + fr][0];
    b1 = *(const bf16x8*)&Bbuf[cur][4 + fs][192 + wq * 16 + fr][0];
    if (pf) STAGE_CHUNK(nxt, ktn, 3);
    __builtin_amdgcn_s_barrier();
    asm volatile("s_waitcnt lgkmcnt(0)" ::: "memory");
    MFMA16(af, b0, b1, 2, 3);
    if (pf) asm volatile("s_waitcnt vmcnt(4)" ::: "memory");
    __builtin_amdgcn_s_barrier();
  }

  gemm_epilogue<EPI>(acc, smem, Cf, Cb, bias, scale, N, (long)bz * sC,
                     bm, bn, wm, wq, tid, lane);
}

// ---------------------------------------------------------------------------
// Row softmax over S [(nb)*LQ][LKK] bf16 (already scaled) -> P bf16, in-place
// capable. km/qm pointers pre-offset to the batch range.
// ---------------------------------------------------------------------------
__global__ __launch_bounds__(256)
void softmax_kernel(const bf16_t* __restrict__ S, bf16_t* __restrict__ P,
                    const float* __restrict__ km, const float* __restrict__ qm)
{
  __shared__ float red[8];
  const int r = blockIdx.x;
  const int b = r >> 11;
  const int t = threadIdx.x;
  const bf16_t* row = S + (long)r * LKK;

  const bf16x8 sv = *(const bf16x8*)(row + t * 8);
  const float4 k0 = ((const float4*)(km + (long)b * LKK))[2 * t];
  const float4 k1 = ((const float4*)(km + (long)b * LKK))[2 * t + 1];
  const float kmv[8] = {k0.x, k0.y, k0.z, k0.w, k1.x, k1.y, k1.z, k1.w};

  float v[8];
  float mx = -3.4e38f;
#pragma unroll
  for (int i = 0; i < 8; i++) {
    float s = (float)sv[i];
    s = (kmv[i] == 0.0f) ? -4294967295.0f : s;   // NEG_INF
    v[i] = s;
    mx = fmaxf(mx, s);
  }
  mx = wred_max(mx);
  if ((t & 63) == 0) red[t >> 6] = mx;
  __syncthreads();
  mx = fmaxf(fmaxf(red[0], red[1]), fmaxf(red[2], red[3]));

  float sum = 0.0f;
#pragma unroll
  for (int i = 0; i < 8; i++) {
    const float e = __expf(v[i] - mx);
    v[i] = e;
    sum += e;
  }
  sum = wred_sum(sum);
  if ((t & 63) == 0) red[4 + (t >> 6)] = sum;
  __syncthreads();
  sum = red[4] + red[5] + red[6] + red[7];

  const float rs = qm[r] / sum;
  bf16x8 o;
#pragma unroll
  for (int i = 0; i < 8; i++) o[i] = f2bf(v[i] * rs);
  *(bf16x8*)(P + (long)r * LKK + t * 8) = o;
}

// ---------------------------------------------------------------------------
// Fused residual + LayerNorm: Y = LN(X + R)*w + b  (rows of EMBD)
// MODE bit0: X bf16 (else f32); bit1: R bf16; bit2: Y bf16 (else f32).
// ---------------------------------------------------------------------------
template<int MODE>
__global__ __launch_bounds__(256)
void ln_kernel(const void* __restrict__ Xv, const void* __restrict__ Rv,
               const float* __restrict__ w, const float* __restrict__ bp,
               void* __restrict__ Yv)
{
  __shared__ float red[8];
  const long r = blockIdx.x;
  const int t = threadIdx.x;

  float x0, x1, x2, x3;
  if constexpr (MODE & 1) {
    const bf16x4 xv = ((const bf16x4*)((const bf16_t*)Xv + r * EMBD))[t];
    x0 = (float)xv[0]; x1 = (float)xv[1]; x2 = (float)xv[2]; x3 = (float)xv[3];
  } else {
    const float4 xv = ((const float4*)((const float*)Xv + r * EMBD))[t];
    x0 = xv.x; x1 = xv.y; x2 = xv.z; x3 = xv.w;
  }
  float r0, r1, r2, r3;
  if constexpr (MODE & 2) {
    const bf16x4 rv = ((const bf16x4*)((const bf16_t*)Rv + r * EMBD))[t];
    r0 = (float)rv[0]; r1 = (float)rv[1]; r2 = (float)rv[2]; r3 = (float)rv[3];
  } else {
    const float4 rv = ((const float4*)((const float*)Rv + r * EMBD))[t];
    r0 = rv.x; r1 = rv.y; r2 = rv.z; r3 = rv.w;
  }
  const float s0 = x0 + r0, s1 = x1 + r1, s2 = x2 + r2, s3 = x3 + r3;

  float sum = wred_sum(s0 + s1 + s2 + s3);
  if ((t & 63) == 0) red[t >> 6] = sum;
  __syncthreads();
  const float mu = (red[0] + red[1] + red[2] + red[3]) * (1.0f / EMBD);

  const float d0 = s0 - mu, d1 = s1 - mu, d2 = s2 - mu, d3 = s3 - mu;
  float sq = wred_sum(d0 * d0 + d1 * d1 + d2 * d2 + d3 * d3);
  if ((t & 63) == 0) red[4 + (t >> 6)] = sq;
  __syncthreads();
  const float var = (red[4] + red[5] + red[6] + red[7]) * (1.0f / EMBD);
  const float rstd = rsqrtf(var + 1e-5f);

  const float4 wv = ((const float4*)w)[t];
  const float4 bv = ((const float4*)bp)[t];
  const float y0 = d0 * rstd * wv.x + bv.x;
  const float y1 = d1 * rstd * wv.y + bv.y;
  const float y2 = d2 * rstd * wv.z + bv.z;
  const float y3 = d3 * rstd * wv.w + bv.w;

  if constexpr (MODE & 4) {
    bf16x4 o; o[0] = f2bf(y0); o[1] = f2bf(y1); o[2] = f2bf(y2); o[3] = f2bf(y3);
    ((bf16x4*)((bf16_t*)Yv + r * EMBD))[t] = o;
  } else {
    ((float4*)((float*)Yv + r * EMBD))[t] = make_float4(y0, y1, y2, y3);
  }
}

// flat f32 -> bf16 (vectorized, grid-stride)
__global__ void cvt_kernel(const float* __restrict__ in, bf16_t* __restrict__ out, long n4)
{
  long i = (long)blockIdx.x * 256 + threadIdx.x;
  const long stride = (long)gridDim.x * 256;
  for (; i < n4; i += stride) {
    const float4 v = ((const float4*)in)[i];
    bf16x4 o; o[0] = f2bf(v.x); o[1] = f2bf(v.y); o[2] = f2bf(v.z); o[3] = f2bf(v.w);
    ((bf16x4*)out)[i] = o;
  }
}

// batched [z][rows][cols] f32 -> transposed bf16 [z][cols][rows] AND straight
// bf16 copy [z][rows][cols] in one read pass.
__global__ __launch_bounds__(256)
void transpose_cvt(const float* __restrict__ in, bf16_t* __restrict__ outT,
                   bf16_t* __restrict__ outS, int rows, int cols)
{
  __shared__ bf16_t tile[32][33];
  const long zb = (long)blockIdx.z * rows * cols;
  const int cb = blockIdx.x * 32;
  const int rb = blockIdx.y * 32;
  const int tx = threadIdx.x & 31;
  const int ty = threadIdx.x >> 5;
#pragma unroll
  for (int i = 0; i < 4; i++) {
    const int rr = ty + i * 8;
    const bf16_t v = f2bf(in[zb + (long)(rb + rr) * cols + cb + tx]);
    tile[rr][tx] = v;
    if (outS != nullptr) outS[zb + (long)(rb + rr) * cols + cb + tx] = v;
  }
  __syncthreads();
#pragma unroll
  for (int i = 0; i < 4; i++) {
    const int cc = ty + i * 8;
    outT[zb + (long)(cb + cc) * rows + rb + tx] = tile[tx][cc];
  }
}

// ---------------------------------------------------------------------------
extern "C" void kernel_launch(void* const* d_in, const int* in_sizes, int n_in,
                              void* d_out, int out_size, void* d_ws, size_t ws_size,
                              hipStream_t stream)
{
  const float* q    = (const float*)d_in[0];
  const float* k    = (const float*)d_in[1];
  const float* qm   = (const float*)d_in[2];
  const float* km   = (const float*)d_in[3];
  const float* lnw  = (const float*)d_in[4];
  const float* lnb  = (const float*)d_in[5];
  const float* ln2w = (const float*)d_in[6];
  const float* ln2b = (const float*)d_in[7];
  const float* W1   = (const float*)d_in[8];
  const float* b1   = (const float*)d_in[9];
  const float* W2   = (const float*)d_in[10];
  const float* b2   = (const float*)d_in[11];

  char* ws = (char*)d_ws;
  char* ob = (char*)d_out;
  const float scale = 0.03125f;             // 1/(sqrt(1024)+1e-8)
  const long MB = 1L << 20;
  const long QE = (long)LQ * EMBD;
  const long SS = (long)LQ * LKK;

  if (ws_size >= 100 * MB) {
    // ================= Tier A: fully batched (z=8) =================
    bf16_t* Qb   = (bf16_t*)ws;
    bf16_t* attn = (bf16_t*)ws;                  // overlays Qb (dead after QK)
    bf16_t* Kb   = (bf16_t*)(ws + 32 * MB);
    bf16_t* h    = (bf16_t*)(ws + 32 * MB);      // overlays Kb (dead after QK)
    bf16_t* Kt   = (bf16_t*)(ws + 64 * MB);
    bf16_t* W1b  = (bf16_t*)(ws + 96 * MB);
    bf16_t* W2b  = (bf16_t*)(ws + 98 * MB);
    bf16_t* Sb   = (bf16_t*)ob;
    float*  y    = (float*)ob;

    cvt_kernel<<<1024, 256, 0, stream>>>(W1, W1b, (long)EMBD * EMBD / 4);
    cvt_kernel<<<1024, 256, 0, stream>>>(W2, W2b, (long)EMBD * EMBD / 4);
    cvt_kernel<<<4096, 256, 0, stream>>>(q, Qb, (long)NB * QE / 4);
    transpose_cvt<<<dim3(EMBD / 32, LKK / 32, NB), 256, 0, stream>>>(k, Kt, Kb, LKK, EMBD);

    // S = (Q K^T)/32   [2-phase CONTROL, ~113us]
    gemm_nt<0><<<dim3(LQ / 256, LKK / 256, NB), 512, 0, stream>>>(
        Qb, Kb, nullptr, Sb, nullptr, scale, LQ, LKK, EMBD, QE, QE, SS);
    // P = qmask * softmax(mask(S))   (in-place)
    softmax_kernel<<<NB * LQ, 256, 0, stream>>>(Sb, Sb, km, qm);
    // attn = P @ K    [8-phase EXPERIMENT -- the clean A/B read]
    gemm_nt8<1><<<dim3(LQ / 256, EMBD / 256, NB), 512, 0, stream>>>(
        Sb, Kt, nullptr, attn, nullptr, 0.0f, LQ, EMBD, LKK, SS, (long)EMBD * LKK, QE);
    // x = LN(attn + q) in-place
    ln_kernel<5><<<NB * LQ, 256, 0, stream>>>(attn, q, lnw, lnb, attn);
    // FFN (2-phase)
    gemm_nt<2><<<dim3(NB * LQ / 256, EMBD / 256, 1), 512, 0, stream>>>(
        attn, W1b, nullptr, h, b1, 0.0f, NB * LQ, EMBD, EMBD, 0, 0, 0);
    gemm_nt<3><<<dim3(NB * LQ / 256, EMBD / 256, 1), 512, 0, stream>>>(
        h, W2b, y, nullptr, b2, 0.0f, NB * LQ, EMBD, EMBD, 0, 0, 0);
    // out = LN(y + x) in-place
    ln_kernel<2><<<NB * LQ, 256, 0, stream>>>(y, attn, ln2w, ln2b, y);

  } else if (ws_size >= 52 * MB) {
    // ================= Tier B: two half-batches (z=4) =================
    bf16_t* attn = (bf16_t*)ws;
    bf16_t* W1b  = (bf16_t*)(ws + 32 * MB);
    bf16_t* W2b  = (bf16_t*)(ws + 34 * MB);
    bf16_t* Kth  = (bf16_t*)(ws + 36 * MB);
    bf16_t* h    = (bf16_t*)(ws + 36 * MB);
    bf16_t* Sb   = (bf16_t*)ob;
    bf16_t* Qbh  = (bf16_t*)(ob + 32 * MB);
    bf16_t* Kbh  = (bf16_t*)(ob + 48 * MB);
    float*  y    = (float*)ob;

    cvt_kernel<<<1024, 256, 0, stream>>>(W1, W1b, (long)EMBD * EMBD / 4);
    cvt_kernel<<<1024, 256, 0, stream>>>(W2, W2b, (long)EMBD * EMBD / 4);

    for (int it = 0; it < 2; it++) {
      const int bo = it * 4;
      const float* qh = q + bo * QE;
      const float* kh = k + bo * QE;
      cvt_kernel<<<2048, 256, 0, stream>>>(qh, Qbh, 4 * QE / 4);
      transpose_cvt<<<dim3(EMBD / 32, LKK / 32, 4), 256, 0, stream>>>(kh, Kth, Kbh, LKK, EMBD);

      gemm_nt<0><<<dim3(LQ / 256, LKK / 256, 4), 512, 0, stream>>>(
          Qbh, Kbh, nullptr, Sb, nullptr, scale, LQ, LKK, EMBD, QE, QE, SS);
      softmax_kernel<<<4 * LQ, 256, 0, stream>>>(Sb, Sb, km + bo * LKK, qm + bo * LQ);
      gemm_nt<1><<<dim3(LQ / 256, EMBD / 256, 4), 512, 0, stream>>>(
          Sb, Kth, nullptr, attn + bo * QE, nullptr, 0.0f, LQ, EMBD, LKK,
          SS, (long)EMBD * LKK, QE);
    }
    ln_kernel<5><<<NB * LQ, 256, 0, stream>>>(attn, q, lnw, lnb, attn);
    for (int c = 0; c < 2; c++) {
      bf16_t* xc = attn + (long)c * 8192 * EMBD;
      float*  yc = y + (long)c * 8192 * EMBD;
      gemm_nt<2><<<dim3(8192 / 256, EMBD / 256, 1), 512, 0, stream>>>(
          xc, W1b, nullptr, h, b1, 0.0f, 8192, EMBD, EMBD, 0, 0, 0);
      gemm_nt<3><<<dim3(8192 / 256, EMBD / 256, 1), 512, 0, stream>>>(
          h, W2b, yc, nullptr, b2, 0.0f, 8192, EMBD, EMBD, 0, 0, 0);
    }
    ln_kernel<2><<<NB * LQ, 256, 0, stream>>>(y, attn, ln2w, ln2b, y);

  } else {
    // ================= Tier C: per-batch 44 MiB fallback =================
    if (ws_size < 44 * MB) return;
    bf16_t* attn = (bf16_t*)ws;
    bf16_t* W1b  = (bf16_t*)(ws + 32 * MB);
    bf16_t* W2b  = (bf16_t*)(ws + 34 * MB);
    bf16_t* h    = (bf16_t*)(ws + 36 * MB);
    bf16_t* Sb   = (bf16_t*)(ob);
    bf16_t* Pb   = (bf16_t*)(ob + 8 * MB);
    bf16_t* Qbb  = (bf16_t*)(ob + 16 * MB);
    bf16_t* Kbb  = (bf16_t*)(ob + 20 * MB);
    bf16_t* Ktb  = (bf16_t*)(ob + 24 * MB);

    cvt_kernel<<<1024, 256, 0, stream>>>(W1, W1b, (long)EMBD * EMBD / 4);
    cvt_kernel<<<1024, 256, 0, stream>>>(W2, W2b, (long)EMBD * EMBD / 4);

    for (int b = 0; b < NB; b++) {
      const float* qb = q + b * QE;
      const float* kb = k + b * QE;
      cvt_kernel<<<2048, 256, 0, stream>>>(qb, Qbb, QE / 4);
      transpose_cvt<<<dim3(EMBD / 32, LKK / 32, 1), 256, 0, stream>>>(kb, Ktb, Kbb, LKK, EMBD);

      gemm_nt<0><<<dim3(LQ / 256, LKK / 256, 1), 512, 0, stream>>>(
          Qbb, Kbb, nullptr, Sb, nullptr, scale, LQ, LKK, EMBD, 0, 0, 0);
      softmax_kernel<<<LQ, 256, 0, stream>>>(Sb, Pb, km + (long)b * LKK, qm + (long)b * LQ);
      gemm_nt<1><<<dim3(LQ / 256, EMBD / 256, 1), 512, 0, stream>>>(
          Pb, Ktb, nullptr, attn + b * QE, nullptr, 0.0f, LQ, EMBD, LKK, 0, 0, 0);
    }
    ln_kernel<5><<<NB * LQ, 256, 0, stream>>>(attn, q, lnw, lnb, attn);
    for (int c = 0; c < 4; c++) {
      bf16_t* xc = attn + (long)c * 4096 * EMBD;
      float*  yc = (float*)d_out + (long)c * 4096 * EMBD;
      gemm_nt<2><<<dim3(4096 / 256, EMBD / 256, 1), 512, 0, stream>>>(
          xc, W1b, nullptr, h, b1, 0.0f, 4096, EMBD, EMBD, 0, 0, 0);
      gemm_nt<3><<<dim3(4096 / 256, EMBD / 256, 1), 512, 0, stream>>>(
          h, W2b, yc, nullptr, b2, 0.0f, 4096, EMBD, EMBD, 0, 0, 0);
      ln_kernel<2><<<4096, 256, 0, stream>>>(yc, xc, ln2w, ln2b, yc);
    }
  }
}

// Round 13
// 430.536 us; speedup vs baseline: 1.3516x; 1.0400x over previous
//
#include <hip/hip_runtime.h>
#include <hip/hip_bf16.h>
#include <stdint.h>

// Problem constants (fixed by setup_inputs)
#define NB    8
#define LQ    2048
#define LKK   2048
#define EMBD  1024

typedef __bf16 bf16_t;
typedef __bf16 bf16x8 __attribute__((ext_vector_type(8)));
typedef __bf16 bf16x4 __attribute__((ext_vector_type(4)));
typedef float  f32x4  __attribute__((ext_vector_type(4)));

// RNE float->bf16, branch-free (inputs are finite)
__device__ __forceinline__ bf16_t f2bf(float x) {
  union { float f; uint32_t u; } v; v.f = x;
  uint32_t r = v.u + 0x7fffu + ((v.u >> 16) & 1u);
  uint16_t h = (uint16_t)(r >> 16);
  return __builtin_bit_cast(bf16_t, h);
}

__device__ __forceinline__ float wred_sum(float v) {
#pragma unroll
  for (int o = 32; o; o >>= 1) v += __shfl_xor(v, o);
  return v;
}
__device__ __forceinline__ float wred_max(float v) {
#pragma unroll
  for (int o = 32; o; o >>= 1) v = fmaxf(v, __shfl_xor(v, o));
  return v;
}

// Shared epilogue (R10-proven): LDS-bounced coalesced C-write.
// acc[m][n][j] holds C[bm+wm+m*16+(lane>>4)*4+j][bn + n*64 + wq*16 + (lane&15)]
// slab = 256x128 f32 (128 KiB); bit4-XOR on (row>>2)&1 keeps write aliasing
// at free 2-way. Two col-halves of 128; 256 B store segments.
template<int EPI>
__device__ __forceinline__ void gemm_epilogue(
    f32x4 (&acc)[8][4], char* smem, float* Cf, bf16_t* Cb,
    const float* bias, float scale, int N, long cbase,
    int bm, int bn, int wm, int wq, int tid, int lane)
{
  float* slab = (float*)smem;
  const int fr = lane & 15;
#pragma unroll
  for (int h = 0; h < 2; h++) {
    __syncthreads();
#pragma unroll
    for (int nn = 0; nn < 2; nn++) {
      const int n = 2 * h + nn;
      const int colb = nn * 64 + wq * 16 + fr;
#pragma unroll
      for (int m = 0; m < 8; m++) {
        const int rbase = wm + m * 16 + ((lane >> 4) << 2);
#pragma unroll
        for (int j = 0; j < 4; j++) {
          const int row = rbase + j;
          slab[row * 128 + (colb ^ (((row >> 2) & 1) << 4))] = acc[m][n][j];
        }
      }
    }
    __syncthreads();
    const int hcol = bn + h * 128;
    if constexpr (EPI == 3) {
#pragma unroll
      for (int p = 0; p < 16; p++) {
        const int row = p * 16 + (tid >> 5);
        const int c4  = (tid & 31) * 4;
        f32x4 v = *(const f32x4*)&slab[row * 128 + (c4 ^ (((row >> 2) & 1) << 4))];
        const float4 bv = *(const float4*)&bias[hcol + c4];
        v[0] += bv.x; v[1] += bv.y; v[2] += bv.z; v[3] += bv.w;
        *(f32x4*)&Cf[cbase + (long)(bm + row) * N + hcol + c4] = v;
      }
    } else {
#pragma unroll
      for (int p = 0; p < 8; p++) {
        const int row  = p * 32 + (tid >> 4);
        const int c8   = (tid & 15) * 8;
        const int flip = ((row >> 2) & 1) << 4;
        const f32x4 v0 = *(const f32x4*)&slab[row * 128 + (c8 ^ flip)];
        const f32x4 v1 = *(const f32x4*)&slab[row * 128 + ((c8 + 4) ^ flip)];
        const float vv[8] = {v0[0], v0[1], v0[2], v0[3], v1[0], v1[1], v1[2], v1[3]};
        bf16x8 o;
        if constexpr (EPI == 0) {
#pragma unroll
          for (int e = 0; e < 8; e++) o[e] = f2bf(vv[e] * scale);
        } else if constexpr (EPI == 1) {
#pragma unroll
          for (int e = 0; e < 8; e++) o[e] = f2bf(vv[e]);
        } else {
          const float4 b0 = *(const float4*)&bias[hcol + c8];
          const float4 b1 = *(const float4*)&bias[hcol + c8 + 4];
          const float bb[8] = {b0.x, b0.y, b0.z, b0.w, b1.x, b1.y, b1.z, b1.w};
#pragma unroll
          for (int e = 0; e < 8; e++) o[e] = f2bf(fmaxf(vv[e] + bb[e], 0.0f));
        }
        *(bf16x8*)&Cb[cbase + (long)(bm + row) * N + hcol + c8] = o;
      }
    }
  }
}

// ---------------------------------------------------------------------------
// Batched NT GEMM, 256x256, BK=64, counted-vmcnt 4-phase pipeline
// (race-validated R9/R12: refchecked EPI=1,2; EPI=0,3 differ only in the
// shared proven epilogue). 8 waves 2Mx4N, dbuf 128 KiB LDS.
// Per K-tile: 4 phases x 16 MFMA; each phase stages ONE 2-load chunk of
// tile t+1 (c0=A-h0, c1=B-h0, c2=A-h1, c3=B-h1).
// Gating ledger (chunk = 2 loads/wave): prologue c0..c3 = 8 in flight,
// vmcnt(4), barrier. p1-end vmcnt(4) retires c2,c3(t); p3-end vmcnt(4)
// retires c0,c1(t+1). In-flight floats 4-8, never 0 mid-loop (T4). Tail
// drains 0 at p1-end. Every gate precedes a barrier that precedes the
// consuming ds_read. No sched_barrier(0) (m141). No XCD swizzle
// (L3-resident regime, R9 measured -9%).
// LDS K-slice-major [buf][slice8][row256][8]: linear gload_lds dest
// (rule #21), conflict-free ds_read_b128.
// EPI: 0 bf16*scale; 1 bf16; 2 +bias ReLU bf16; 3 +bias f32.
// ---------------------------------------------------------------------------
template<int EPI>
__global__ __launch_bounds__(512, 1)
void gemm_nt8(const bf16_t* __restrict__ A, const bf16_t* __restrict__ B,
              float* __restrict__ Cf, bf16_t* __restrict__ Cb,
              const float* __restrict__ bias, float scale,
              int M, int N, int K, long sA, long sB, long sC)
{
  __shared__ __align__(16) char smem[131072];
  typedef bf16_t ldsbuf_t[8][256][8];
  ldsbuf_t* Abuf = (ldsbuf_t*)smem;
  ldsbuf_t* Bbuf = (ldsbuf_t*)(smem + 65536);

  const int tid  = threadIdx.x;
  const int lane = tid & 63;
  const int wave = tid >> 6;
  const int wq   = wave & 3;
  const int bz   = blockIdx.z;

  const bf16_t* Ab = A + (long)bz * sA;
  const bf16_t* Bb = B + (long)bz * sB;

  const int bm = blockIdx.x * 256;
  const int bn = blockIdx.y * 256;
  const int wm = (wave >> 2) * 128;

  f32x4 acc[8][4] = {};

  const int fr = lane & 15;
  const int fs = lane >> 4;

  // chunk c: 0 = A slices0-3, 1 = B slices0-3, 2 = A slices4-7, 3 = B slices4-7
  auto STAGE_CHUNK = [&](int bufi, int kt, int c) {
    const bf16_t* src = (c & 1) ? Bb : Ab;
    const int base    = (c & 1) ? bn : bm;
    char* dst = ((c & 1) ? (char*)&Bbuf[bufi][0][0][0] : (char*)&Abuf[bufi][0][0][0])
                + (c >> 1) * 16384;
    const int kofs = kt + (c >> 1) * 32;
#pragma unroll
    for (int i = 0; i < 2; i++) {
      const int slot = tid + i * 512;
      const int slc  = slot >> 8;
      const int row  = slot & 255;
      __builtin_amdgcn_global_load_lds(
        (const __attribute__((address_space(1))) void*)(src + (long)(base + row) * K + kofs + slc * 8),
        (__attribute__((address_space(3))) void*)(dst + slot * 16), 16, 0, 0);
    }
  };

  auto MFMA16 = [&](bf16x8 (&af)[8], bf16x8 bx, bf16x8 by, int n0, int n1) {
    __builtin_amdgcn_s_setprio(1);
#pragma unroll
    for (int m = 0; m < 8; m++)
      acc[m][n0] = __builtin_amdgcn_mfma_f32_16x16x32_bf16(af[m], bx, acc[m][n0], 0, 0, 0);
#pragma unroll
    for (int m = 0; m < 8; m++)
      acc[m][n1] = __builtin_amdgcn_mfma_f32_16x16x32_bf16(af[m], by, acc[m][n1], 0, 0, 0);
    __builtin_amdgcn_s_setprio(0);
  };

  const int nt = K >> 6;

  STAGE_CHUNK(0, 0, 0); STAGE_CHUNK(0, 0, 1);
  STAGE_CHUNK(0, 0, 2); STAGE_CHUNK(0, 0, 3);
  asm volatile("s_waitcnt vmcnt(4)" ::: "memory");
  __builtin_amdgcn_s_barrier();

  for (int t = 0; t < nt; ++t) {
    const int cur = t & 1, nxt = cur ^ 1;
    const bool pf = (t + 1 < nt);
    const int ktn = (t + 1) << 6;
    bf16x8 af[8], b0, b1;

    // phase 0: kk=0, n{0,1}; stage c0(t+1). [c0,c1(t) gated at t-1.p3]
#pragma unroll
    for (int m = 0; m < 8; m++) af[m] = *(const bf16x8*)&Abuf[cur][fs][wm + m * 16 + fr][0];
    b0 = *(const bf16x8*)&Bbuf[cur][fs][wq * 16 + fr][0];
    b1 = *(const bf16x8*)&Bbuf[cur][fs][64 + wq * 16 + fr][0];
    if (pf) STAGE_CHUNK(nxt, ktn, 0);
    __builtin_amdgcn_s_barrier();
    asm volatile("s_waitcnt lgkmcnt(0)" ::: "memory");
    MFMA16(af, b0, b1, 0, 1);
    __builtin_amdgcn_s_barrier();

    // phase 1: kk=0, n{2,3}; stage c1(t+1); GATE c2,c3(t) at end.
    b0 = *(const bf16x8*)&Bbuf[cur][fs][128 + wq * 16 + fr][0];
    b1 = *(const bf16x8*)&Bbuf[cur][fs][192 + wq * 16 + fr][0];
    if (pf) STAGE_CHUNK(nxt, ktn, 1);
    __builtin_amdgcn_s_barrier();
    asm volatile("s_waitcnt lgkmcnt(0)" ::: "memory");
    MFMA16(af, b0, b1, 2, 3);
    if (pf) asm volatile("s_waitcnt vmcnt(4)" ::: "memory");
    else    asm volatile("s_waitcnt vmcnt(0)" ::: "memory");
    __builtin_amdgcn_s_barrier();

    // phase 2: kk=1, n{0,1}; stage c2(t+1).
#pragma unroll
    for (int m = 0; m < 8; m++) af[m] = *(const bf16x8*)&Abuf[cur][4 + fs][wm + m * 16 + fr][0];
    b0 = *(const bf16x8*)&Bbuf[cur][4 + fs][wq * 16 + fr][0];
    b1 = *(const bf16x8*)&Bbuf[cur][4 + fs][64 + wq * 16 + fr][0];
    if (pf) STAGE_CHUNK(nxt, ktn, 2);
    __builtin_amdgcn_s_barrier();
    asm volatile("s_waitcnt lgkmcnt(0)" ::: "memory");
    MFMA16(af, b0, b1, 0, 1);
    __builtin_amdgcn_s_barrier();

    // phase 3: kk=1, n{2,3}; stage c3(t+1); GATE c0,c1(t+1) at end.
    b0 = *(const bf16x8*)&Bbuf[cur][4 + fs][128 + wq * 16 + fr][0];
    b1 = *(const bf16x8*)&Bbuf[cur][4 + fs][192 + wq * 16 + fr][0];
    if (pf) STAGE_CHUNK(nxt, ktn, 3);
    __builtin_amdgcn_s_barrier();
    asm volatile("s_waitcnt lgkmcnt(0)" ::: "memory");
    MFMA16(af, b0, b1, 2, 3);
    if (pf) asm volatile("s_waitcnt vmcnt(4)" ::: "memory");
    __builtin_amdgcn_s_barrier();
  }

  gemm_epilogue<EPI>(acc, smem, Cf, Cb, bias, scale, N, (long)bz * sC,
                     bm, bn, wm, wq, tid, lane);
}

// ---------------------------------------------------------------------------
// Row softmax over S [(nb)*LQ][LKK] bf16 (already scaled) -> P bf16, in-place
// capable. km/qm pointers pre-offset to the batch range.
// ---------------------------------------------------------------------------
__global__ __launch_bounds__(256)
void softmax_kernel(const bf16_t* __restrict__ S, bf16_t* __restrict__ P,
                    const float* __restrict__ km, const float* __restrict__ qm)
{
  __shared__ float red[8];
  const int r = blockIdx.x;
  const int b = r >> 11;
  const int t = threadIdx.x;
  const bf16_t* row = S + (long)r * LKK;

  const bf16x8 sv = *(const bf16x8*)(row + t * 8);
  const float4 k0 = ((const float4*)(km + (long)b * LKK))[2 * t];
  const float4 k1 = ((const float4*)(km + (long)b * LKK))[2 * t + 1];
  const float kmv[8] = {k0.x, k0.y, k0.z, k0.w, k1.x, k1.y, k1.z, k1.w};

  float v[8];
  float mx = -3.4e38f;
#pragma unroll
  for (int i = 0; i < 8; i++) {
    float s = (float)sv[i];
    s = (kmv[i] == 0.0f) ? -4294967295.0f : s;   // NEG_INF
    v[i] = s;
    mx = fmaxf(mx, s);
  }
  mx = wred_max(mx);
  if ((t & 63) == 0) red[t >> 6] = mx;
  __syncthreads();
  mx = fmaxf(fmaxf(red[0], red[1]), fmaxf(red[2], red[3]));

  float sum = 0.0f;
#pragma unroll
  for (int i = 0; i < 8; i++) {
    const float e = __expf(v[i] - mx);
    v[i] = e;
    sum += e;
  }
  sum = wred_sum(sum);
  if ((t & 63) == 0) red[4 + (t >> 6)] = sum;
  __syncthreads();
  sum = red[4] + red[5] + red[6] + red[7];

  const float rs = qm[r] / sum;
  bf16x8 o;
#pragma unroll
  for (int i = 0; i < 8; i++) o[i] = f2bf(v[i] * rs);
  *(bf16x8*)(P + (long)r * LKK + t * 8) = o;
}

// ---------------------------------------------------------------------------
// Fused residual + LayerNorm: Y = LN(X + R)*w + b  (rows of EMBD)
// MODE bit0: X bf16 (else f32); bit1: R bf16; bit2: Y bf16 (else f32).
// ---------------------------------------------------------------------------
template<int MODE>
__global__ __launch_bounds__(256)
void ln_kernel(const void* __restrict__ Xv, const void* __restrict__ Rv,
               const float* __restrict__ w, const float* __restrict__ bp,
               void* __restrict__ Yv)
{
  __shared__ float red[8];
  const long r = blockIdx.x;
  const int t = threadIdx.x;

  float x0, x1, x2, x3;
  if constexpr (MODE & 1) {
    const bf16x4 xv = ((const bf16x4*)((const bf16_t*)Xv + r * EMBD))[t];
    x0 = (float)xv[0]; x1 = (float)xv[1]; x2 = (float)xv[2]; x3 = (float)xv[3];
  } else {
    const float4 xv = ((const float4*)((const float*)Xv + r * EMBD))[t];
    x0 = xv.x; x1 = xv.y; x2 = xv.z; x3 = xv.w;
  }
  float r0, r1, r2, r3;
  if constexpr (MODE & 2) {
    const bf16x4 rv = ((const bf16x4*)((const bf16_t*)Rv + r * EMBD))[t];
    r0 = (float)rv[0]; r1 = (float)rv[1]; r2 = (float)rv[2]; r3 = (float)rv[3];
  } else {
    const float4 rv = ((const float4*)((const float*)Rv + r * EMBD))[t];
    r0 = rv.x; r1 = rv.y; r2 = rv.z; r3 = rv.w;
  }
  const float s0 = x0 + r0, s1 = x1 + r1, s2 = x2 + r2, s3 = x3 + r3;

  float sum = wred_sum(s0 + s1 + s2 + s3);
  if ((t & 63) == 0) red[t >> 6] = sum;
  __syncthreads();
  const float mu = (red[0] + red[1] + red[2] + red[3]) * (1.0f / EMBD);

  const float d0 = s0 - mu, d1 = s1 - mu, d2 = s2 - mu, d3 = s3 - mu;
  float sq = wred_sum(d0 * d0 + d1 * d1 + d2 * d2 + d3 * d3);
  if ((t & 63) == 0) red[4 + (t >> 6)] = sq;
  __syncthreads();
  const float var = (red[4] + red[5] + red[6] + red[7]) * (1.0f / EMBD);
  const float rstd = rsqrtf(var + 1e-5f);

  const float4 wv = ((const float4*)w)[t];
  const float4 bv = ((const float4*)bp)[t];
  const float y0 = d0 * rstd * wv.x + bv.x;
  const float y1 = d1 * rstd * wv.y + bv.y;
  const float y2 = d2 * rstd * wv.z + bv.z;
  const float y3 = d3 * rstd * wv.w + bv.w;

  if constexpr (MODE & 4) {
    bf16x4 o; o[0] = f2bf(y0); o[1] = f2bf(y1); o[2] = f2bf(y2); o[3] = f2bf(y3);
    ((bf16x4*)((bf16_t*)Yv + r * EMBD))[t] = o;
  } else {
    ((float4*)((float*)Yv + r * EMBD))[t] = make_float4(y0, y1, y2, y3);
  }
}

// flat f32 -> bf16 (vectorized, grid-stride)
__global__ void cvt_kernel(const float* __restrict__ in, bf16_t* __restrict__ out, long n4)
{
  long i = (long)blockIdx.x * 256 + threadIdx.x;
  const long stride = (long)gridDim.x * 256;
  for (; i < n4; i += stride) {
    const float4 v = ((const float4*)in)[i];
    bf16x4 o; o[0] = f2bf(v.x); o[1] = f2bf(v.y); o[2] = f2bf(v.z); o[3] = f2bf(v.w);
    ((bf16x4*)out)[i] = o;
  }
}

// batched [z][rows][cols] f32 -> transposed bf16 [z][cols][rows] AND straight
// bf16 copy [z][rows][cols] in one read pass.
__global__ __launch_bounds__(256)
void transpose_cvt(const float* __restrict__ in, bf16_t* __restrict__ outT,
                   bf16_t* __restrict__ outS, int rows, int cols)
{
  __shared__ bf16_t tile[32][33];
  const long zb = (long)blockIdx.z * rows * cols;
  const int cb = blockIdx.x * 32;
  const int rb = blockIdx.y * 32;
  const int tx = threadIdx.x & 31;
  const int ty = threadIdx.x >> 5;
#pragma unroll
  for (int i = 0; i < 4; i++) {
    const int rr = ty + i * 8;
    const bf16_t v = f2bf(in[zb + (long)(rb + rr) * cols + cb + tx]);
    tile[rr][tx] = v;
    if (outS != nullptr) outS[zb + (long)(rb + rr) * cols + cb + tx] = v;
  }
  __syncthreads();
#pragma unroll
  for (int i = 0; i < 4; i++) {
    const int cc = ty + i * 8;
    outT[zb + (long)(cb + cc) * rows + rb + tx] = tile[tx][cc];
  }
}

// ---------------------------------------------------------------------------
extern "C" void kernel_launch(void* const* d_in, const int* in_sizes, int n_in,
                              void* d_out, int out_size, void* d_ws, size_t ws_size,
                              hipStream_t stream)
{
  const float* q    = (const float*)d_in[0];
  const float* k    = (const float*)d_in[1];
  const float* qm   = (const float*)d_in[2];
  const float* km   = (const float*)d_in[3];
  const float* lnw  = (const float*)d_in[4];
  const float* lnb  = (const float*)d_in[5];
  const float* ln2w = (const float*)d_in[6];
  const float* ln2b = (const float*)d_in[7];
  const float* W1   = (const float*)d_in[8];
  const float* b1   = (const float*)d_in[9];
  const float* W2   = (const float*)d_in[10];
  const float* b2   = (const float*)d_in[11];

  char* ws = (char*)d_ws;
  char* ob = (char*)d_out;
  const float scale = 0.03125f;             // 1/(sqrt(1024)+1e-8)
  const long MB = 1L << 20;
  const long QE = (long)LQ * EMBD;
  const long SS = (long)LQ * LKK;

  if (ws_size >= 100 * MB) {
    // ================= Tier A: fully batched (z=8) =================
    bf16_t* Qb   = (bf16_t*)ws;
    bf16_t* attn = (bf16_t*)ws;                  // overlays Qb (dead after QK)
    bf16_t* Kb   = (bf16_t*)(ws + 32 * MB);
    bf16_t* h    = (bf16_t*)(ws + 32 * MB);      // overlays Kb (dead after QK)
    bf16_t* Kt   = (bf16_t*)(ws + 64 * MB);
    bf16_t* W1b  = (bf16_t*)(ws + 96 * MB);
    bf16_t* W2b  = (bf16_t*)(ws + 98 * MB);
    bf16_t* Sb   = (bf16_t*)ob;
    float*  y    = (float*)ob;

    cvt_kernel<<<1024, 256, 0, stream>>>(W1, W1b, (long)EMBD * EMBD / 4);
    cvt_kernel<<<1024, 256, 0, stream>>>(W2, W2b, (long)EMBD * EMBD / 4);
    cvt_kernel<<<4096, 256, 0, stream>>>(q, Qb, (long)NB * QE / 4);
    transpose_cvt<<<dim3(EMBD / 32, LKK / 32, NB), 256, 0, stream>>>(k, Kt, Kb, LKK, EMBD);

    // S = (Q K^T)/32   [8-phase -- the decisive top-5 read]
    gemm_nt8<0><<<dim3(LQ / 256, LKK / 256, NB), 512, 0, stream>>>(
        Qb, Kb, nullptr, Sb, nullptr, scale, LQ, LKK, EMBD, QE, QE, SS);
    // P = qmask * softmax(mask(S))   (in-place)
    softmax_kernel<<<NB * LQ, 256, 0, stream>>>(Sb, Sb, km, qm);
    // attn = P @ K    [8-phase, validated R12]
    gemm_nt8<1><<<dim3(LQ / 256, EMBD / 256, NB), 512, 0, stream>>>(
        Sb, Kt, nullptr, attn, nullptr, 0.0f, LQ, EMBD, LKK, SS, (long)EMBD * LKK, QE);
    // x = LN(attn + q) in-place
    ln_kernel<5><<<NB * LQ, 256, 0, stream>>>(attn, q, lnw, lnb, attn);
    // FFN [8-phase]
    gemm_nt8<2><<<dim3(NB * LQ / 256, EMBD / 256, 1), 512, 0, stream>>>(
        attn, W1b, nullptr, h, b1, 0.0f, NB * LQ, EMBD, EMBD, 0, 0, 0);
    gemm_nt8<3><<<dim3(NB * LQ / 256, EMBD / 256, 1), 512, 0, stream>>>(
        h, W2b, y, nullptr, b2, 0.0f, NB * LQ, EMBD, EMBD, 0, 0, 0);
    // out = LN(y + x) in-place
    ln_kernel<2><<<NB * LQ, 256, 0, stream>>>(y, attn, ln2w, ln2b, y);

  } else if (ws_size >= 52 * MB) {
    // ================= Tier B: two half-batches (z=4) =================
    bf16_t* attn = (bf16_t*)ws;
    bf16_t* W1b  = (bf16_t*)(ws + 32 * MB);
    bf16_t* W2b  = (bf16_t*)(ws + 34 * MB);
    bf16_t* Kth  = (bf16_t*)(ws + 36 * MB);
    bf16_t* h    = (bf16_t*)(ws + 36 * MB);
    bf16_t* Sb   = (bf16_t*)ob;
    bf16_t* Qbh  = (bf16_t*)(ob + 32 * MB);
    bf16_t* Kbh  = (bf16_t*)(ob + 48 * MB);
    float*  y    = (float*)ob;

    cvt_kernel<<<1024, 256, 0, stream>>>(W1, W1b, (long)EMBD * EMBD / 4);
    cvt_kernel<<<1024, 256, 0, stream>>>(W2, W2b, (long)EMBD * EMBD / 4);

    for (int it = 0; it < 2; it++) {
      const int bo = it * 4;
      const float* qh = q + bo * QE;
      const float* kh = k + bo * QE;
      cvt_kernel<<<2048, 256, 0, stream>>>(qh, Qbh, 4 * QE / 4);
      transpose_cvt<<<dim3(EMBD / 32, LKK / 32, 4), 256, 0, stream>>>(kh, Kth, Kbh, LKK, EMBD);

      gemm_nt8<0><<<dim3(LQ / 256, LKK / 256, 4), 512, 0, stream>>>(
          Qbh, Kbh, nullptr, Sb, nullptr, scale, LQ, LKK, EMBD, QE, QE, SS);
      softmax_kernel<<<4 * LQ, 256, 0, stream>>>(Sb, Sb, km + bo * LKK, qm + bo * LQ);
      gemm_nt8<1><<<dim3(LQ / 256, EMBD / 256, 4), 512, 0, stream>>>(
          Sb, Kth, nullptr, attn + bo * QE, nullptr, 0.0f, LQ, EMBD, LKK,
          SS, (long)EMBD * LKK, QE);
    }
    ln_kernel<5><<<NB * LQ, 256, 0, stream>>>(attn, q, lnw, lnb, attn);
    for (int c = 0; c < 2; c++) {
      bf16_t* xc = attn + (long)c * 8192 * EMBD;
      float*  yc = y + (long)c * 8192 * EMBD;
      gemm_nt8<2><<<dim3(8192 / 256, EMBD / 256, 1), 512, 0, stream>>>(
          xc, W1b, nullptr, h, b1, 0.0f, 8192, EMBD, EMBD, 0, 0, 0);
      gemm_nt8<3><<<dim3(8192 / 256, EMBD / 256, 1), 512, 0, stream>>>(
          h, W2b, yc, nullptr, b2, 0.0f, 8192, EMBD, EMBD, 0, 0, 0);
    }
    ln_kernel<2><<<NB * LQ, 256, 0, stream>>>(y, attn, ln2w, ln2b, y);

  } else {
    // ================= Tier C: per-batch 44 MiB fallback =================
    if (ws_size < 44 * MB) return;
    bf16_t* attn = (bf16_t*)ws;
    bf16_t* W1b  = (bf16_t*)(ws + 32 * MB);
    bf16_t* W2b  = (bf16_t*)(ws + 34 * MB);
    bf16_t* h    = (bf16_t*)(ws + 36 * MB);
    bf16_t* Sb   = (bf16_t*)(ob);
    bf16_t* Pb   = (bf16_t*)(ob + 8 * MB);
    bf16_t* Qbb  = (bf16_t*)(ob + 16 * MB);
    bf16_t* Kbb  = (bf16_t*)(ob + 20 * MB);
    bf16_t* Ktb  = (bf16_t*)(ob + 24 * MB);

    cvt_kernel<<<1024, 256, 0, stream>>>(W1, W1b, (long)EMBD * EMBD / 4);
    cvt_kernel<<<1024, 256, 0, stream>>>(W2, W2b, (long)EMBD * EMBD / 4);

    for (int b = 0; b < NB; b++) {
      const float* qb = q + b * QE;
      const float* kb = k + b * QE;
      cvt_kernel<<<2048, 256, 0, stream>>>(qb, Qbb, QE / 4);
      transpose_cvt<<<dim3(EMBD / 32, LKK / 32, 1), 256, 0, stream>>>(kb, Ktb, Kbb, LKK, EMBD);

      gemm_nt8<0><<<dim3(LQ / 256, LKK / 256, 1), 512, 0, stream>>>(
          Qbb, Kbb, nullptr, Sb, nullptr, scale, LQ, LKK, EMBD, 0, 0, 0);
      softmax_kernel<<<LQ, 256, 0, stream>>>(Sb, Pb, km + (long)b * LKK, qm + (long)b * LQ);
      gemm_nt8<1><<<dim3(LQ / 256, EMBD / 256, 1), 512, 0, stream>>>(
          Pb, Ktb, nullptr, attn + b * QE, nullptr, 0.0f, LQ, EMBD, LKK, 0, 0, 0);
    }
    ln_kernel<5><<<NB * LQ, 256, 0, stream>>>(attn, q, lnw, lnb, attn);
    for (int c = 0; c < 4; c++) {
      bf16_t* xc = attn + (long)c * 4096 * EMBD;
      float*  yc = (float*)d_out + (long)c * 4096 * EMBD;
      gemm_nt8<2><<<dim3(4096 / 256, EMBD / 256, 1), 512, 0, stream>>>(
          xc, W1b, nullptr, h, b1, 0.0f, 4096, EMBD, EMBD, 0, 0, 0);
      gemm_nt8<3><<<dim3(4096 / 256, EMBD / 256, 1), 512, 0, stream>>>(
          h, W2b, yc, nullptr, b2, 0.0f, 4096, EMBD, EMBD, 0, 0, 0);
      ln_kernel<2><<<4096, 256, 0, stream>>>(yc, xc, ln2w, ln2b, yc);
    }
  }
}

// Round 14
// 423.050 us; speedup vs baseline: 1.3756x; 1.0177x over previous
//
#include <hip/hip_runtime.h>
#include <hip/hip_bf16.h>
#include <stdint.h>

// Problem constants (fixed by setup_inputs)
#define NB    8
#define LQ    2048
#define LKK   2048
#define EMBD  1024

typedef __bf16 bf16_t;
typedef __bf16 bf16x8 __attribute__((ext_vector_type(8)));
typedef __bf16 bf16x4 __attribute__((ext_vector_type(4)));
typedef float  f32x4  __attribute__((ext_vector_type(4)));

// RNE float->bf16, branch-free (inputs are finite)
__device__ __forceinline__ bf16_t f2bf(float x) {
  union { float f; uint32_t u; } v; v.f = x;
  uint32_t r = v.u + 0x7fffu + ((v.u >> 16) & 1u);
  uint16_t h = (uint16_t)(r >> 16);
  return __builtin_bit_cast(bf16_t, h);
}

__device__ __forceinline__ float wred_sum(float v) {
#pragma unroll
  for (int o = 32; o; o >>= 1) v += __shfl_xor(v, o);
  return v;
}
__device__ __forceinline__ float wred_max(float v) {
#pragma unroll
  for (int o = 32; o; o >>= 1) v = fmaxf(v, __shfl_xor(v, o));
  return v;
}

// Shared epilogue (R10-proven): LDS-bounced coalesced C-write.
// acc[m][n][j] holds C[bm+wm+m*16+(lane>>4)*4+j][bn + n*64 + wq*16 + (lane&15)]
// slab = 256x128 f32 (128 KiB); bit4-XOR on (row>>2)&1 keeps write aliasing
// at free 2-way. Two col-halves of 128; 256 B store segments.
// EPI: 0 bf16*scale; 1 bf16; 2 +bias ReLU bf16; 3 +bias f32; 4 +bias bf16.
template<int EPI>
__device__ __forceinline__ void gemm_epilogue(
    f32x4 (&acc)[8][4], char* smem, float* Cf, bf16_t* Cb,
    const float* bias, float scale, int N, long cbase,
    int bm, int bn, int wm, int wq, int tid, int lane)
{
  float* slab = (float*)smem;
  const int fr = lane & 15;
#pragma unroll
  for (int h = 0; h < 2; h++) {
    __syncthreads();
#pragma unroll
    for (int nn = 0; nn < 2; nn++) {
      const int n = 2 * h + nn;
      const int colb = nn * 64 + wq * 16 + fr;
#pragma unroll
      for (int m = 0; m < 8; m++) {
        const int rbase = wm + m * 16 + ((lane >> 4) << 2);
#pragma unroll
        for (int j = 0; j < 4; j++) {
          const int row = rbase + j;
          slab[row * 128 + (colb ^ (((row >> 2) & 1) << 4))] = acc[m][n][j];
        }
      }
    }
    __syncthreads();
    const int hcol = bn + h * 128;
    if constexpr (EPI == 3) {
#pragma unroll
      for (int p = 0; p < 16; p++) {
        const int row = p * 16 + (tid >> 5);
        const int c4  = (tid & 31) * 4;
        f32x4 v = *(const f32x4*)&slab[row * 128 + (c4 ^ (((row >> 2) & 1) << 4))];
        const float4 bv = *(const float4*)&bias[hcol + c4];
        v[0] += bv.x; v[1] += bv.y; v[2] += bv.z; v[3] += bv.w;
        *(f32x4*)&Cf[cbase + (long)(bm + row) * N + hcol + c4] = v;
      }
    } else {
#pragma unroll
      for (int p = 0; p < 8; p++) {
        const int row  = p * 32 + (tid >> 4);
        const int c8   = (tid & 15) * 8;
        const int flip = ((row >> 2) & 1) << 4;
        const f32x4 v0 = *(const f32x4*)&slab[row * 128 + (c8 ^ flip)];
        const f32x4 v1 = *(const f32x4*)&slab[row * 128 + ((c8 + 4) ^ flip)];
        const float vv[8] = {v0[0], v0[1], v0[2], v0[3], v1[0], v1[1], v1[2], v1[3]};
        bf16x8 o;
        if constexpr (EPI == 0) {
#pragma unroll
          for (int e = 0; e < 8; e++) o[e] = f2bf(vv[e] * scale);
        } else if constexpr (EPI == 1) {
#pragma unroll
          for (int e = 0; e < 8; e++) o[e] = f2bf(vv[e]);
        } else if constexpr (EPI == 2) {
          const float4 b0 = *(const float4*)&bias[hcol + c8];
          const float4 b1 = *(const float4*)&bias[hcol + c8 + 4];
          const float bb[8] = {b0.x, b0.y, b0.z, b0.w, b1.x, b1.y, b1.z, b1.w};
#pragma unroll
          for (int e = 0; e < 8; e++) o[e] = f2bf(fmaxf(vv[e] + bb[e], 0.0f));
        } else {   // EPI == 4: +bias, bf16 (no ReLU)
          const float4 b0 = *(const float4*)&bias[hcol + c8];
          const float4 b1 = *(const float4*)&bias[hcol + c8 + 4];
          const float bb[8] = {b0.x, b0.y, b0.z, b0.w, b1.x, b1.y, b1.z, b1.w};
#pragma unroll
          for (int e = 0; e < 8; e++) o[e] = f2bf(vv[e] + bb[e]);
        }
        *(bf16x8*)&Cb[cbase + (long)(bm + row) * N + hcol + c8] = o;
      }
    }
  }
}

// ---------------------------------------------------------------------------
// Batched NT GEMM, 256x256, BK=64, counted-vmcnt 4-phase pipeline
// (race-validated R9/R12/R13; 105us @ QK shape, MfmaUtil 27%).
// 8 waves 2Mx4N, dbuf 128 KiB LDS. Per K-tile: 4 phases x 16 MFMA; each
// phase stages ONE 2-load chunk of tile t+1 (c0=A-h0,c1=B-h0,c2=A-h1,c3=B-h1).
// Gating ledger (chunk = 2 loads/wave): prologue c0..c3 = 8 in flight,
// vmcnt(4), barrier. p1-end vmcnt(4) retires c2,c3(t); p3-end vmcnt(4)
// retires c0,c1(t+1). In-flight floats 4-8, never 0 mid-loop (T4). Tail
// drains 0 at p1-end. No sched_barrier(0) (m141). No XCD swizzle
// (L3-resident regime, R9: -9%).
// LDS K-slice-major [buf][slice8][row256][8]: linear gload_lds dest
// (rule #21), conflict-free ds_read_b128.
// ---------------------------------------------------------------------------
template<int EPI>
__global__ __launch_bounds__(512, 1)
void gemm_nt8(const bf16_t* __restrict__ A, const bf16_t* __restrict__ B,
              float* __restrict__ Cf, bf16_t* __restrict__ Cb,
              const float* __restrict__ bias, float scale,
              int M, int N, int K, long sA, long sB, long sC)
{
  __shared__ __align__(16) char smem[131072];
  typedef bf16_t ldsbuf_t[8][256][8];
  ldsbuf_t* Abuf = (ldsbuf_t*)smem;
  ldsbuf_t* Bbuf = (ldsbuf_t*)(smem + 65536);

  const int tid  = threadIdx.x;
  const int lane = tid & 63;
  const int wave = tid >> 6;
  const int wq   = wave & 3;
  const int bz   = blockIdx.z;

  const bf16_t* Ab = A + (long)bz * sA;
  const bf16_t* Bb = B + (long)bz * sB;

  const int bm = blockIdx.x * 256;
  const int bn = blockIdx.y * 256;
  const int wm = (wave >> 2) * 128;

  f32x4 acc[8][4] = {};

  const int fr = lane & 15;
  const int fs = lane >> 4;

  // chunk c: 0 = A slices0-3, 1 = B slices0-3, 2 = A slices4-7, 3 = B slices4-7
  auto STAGE_CHUNK = [&](int bufi, int kt, int c) {
    const bf16_t* src = (c & 1) ? Bb : Ab;
    const int base    = (c & 1) ? bn : bm;
    char* dst = ((c & 1) ? (char*)&Bbuf[bufi][0][0][0] : (char*)&Abuf[bufi][0][0][0])
                + (c >> 1) * 16384;
    const int kofs = kt + (c >> 1) * 32;
#pragma unroll
    for (int i = 0; i < 2; i++) {
      const int slot = tid + i * 512;
      const int slc  = slot >> 8;
      const int row  = slot & 255;
      __builtin_amdgcn_global_load_lds(
        (const __attribute__((address_space(1))) void*)(src + (long)(base + row) * K + kofs + slc * 8),
        (__attribute__((address_space(3))) void*)(dst + slot * 16), 16, 0, 0);
    }
  };

  auto MFMA16 = [&](bf16x8 (&af)[8], bf16x8 bx, bf16x8 by, int n0, int n1) {
    __builtin_amdgcn_s_setprio(1);
#pragma unroll
    for (int m = 0; m < 8; m++)
      acc[m][n0] = __builtin_amdgcn_mfma_f32_16x16x32_bf16(af[m], bx, acc[m][n0], 0, 0, 0);
#pragma unroll
    for (int m = 0; m < 8; m++)
      acc[m][n1] = __builtin_amdgcn_mfma_f32_16x16x32_bf16(af[m], by, acc[m][n1], 0, 0, 0);
    __builtin_amdgcn_s_setprio(0);
  };

  const int nt = K >> 6;

  STAGE_CHUNK(0, 0, 0); STAGE_CHUNK(0, 0, 1);
  STAGE_CHUNK(0, 0, 2); STAGE_CHUNK(0, 0, 3);
  asm volatile("s_waitcnt vmcnt(4)" ::: "memory");
  __builtin_amdgcn_s_barrier();

  for (int t = 0; t < nt; ++t) {
    const int cur = t & 1, nxt = cur ^ 1;
    const bool pf = (t + 1 < nt);
    const int ktn = (t + 1) << 6;
    bf16x8 af[8], b0, b1;

    // phase 0: kk=0, n{0,1}; stage c0(t+1). [c0,c1(t) gated at t-1.p3]
#pragma unroll
    for (int m = 0; m < 8; m++) af[m] = *(const bf16x8*)&Abuf[cur][fs][wm + m * 16 + fr][0];
    b0 = *(const bf16x8*)&Bbuf[cur][fs][wq * 16 + fr][0];
    b1 = *(const bf16x8*)&Bbuf[cur][fs][64 + wq * 16 + fr][0];
    if (pf) STAGE_CHUNK(nxt, ktn, 0);
    __builtin_amdgcn_s_barrier();
    asm volatile("s_waitcnt lgkmcnt(0)" ::: "memory");
    MFMA16(af, b0, b1, 0, 1);
    __builtin_amdgcn_s_barrier();

    // phase 1: kk=0, n{2,3}; stage c1(t+1); GATE c2,c3(t) at end.
    b0 = *(const bf16x8*)&Bbuf[cur][fs][128 + wq * 16 + fr][0];
    b1 = *(const bf16x8*)&Bbuf[cur][fs][192 + wq * 16 + fr][0];
    if (pf) STAGE_CHUNK(nxt, ktn, 1);
    __builtin_amdgcn_s_barrier();
    asm volatile("s_waitcnt lgkmcnt(0)" ::: "memory");
    MFMA16(af, b0, b1, 2, 3);
    if (pf) asm volatile("s_waitcnt vmcnt(4)" ::: "memory");
    else    asm volatile("s_waitcnt vmcnt(0)" ::: "memory");
    __builtin_amdgcn_s_barrier();

    // phase 2: kk=1, n{0,1}; stage c2(t+1).
#pragma unroll
    for (int m = 0; m < 8; m++) af[m] = *(const bf16x8*)&Abuf[cur][4 + fs][wm + m * 16 + fr][0];
    b0 = *(const bf16x8*)&Bbuf[cur][4 + fs][wq * 16 + fr][0];
    b1 = *(const bf16x8*)&Bbuf[cur][4 + fs][64 + wq * 16 + fr][0];
    if (pf) STAGE_CHUNK(nxt, ktn, 2);
    __builtin_amdgcn_s_barrier();
    asm volatile("s_waitcnt lgkmcnt(0)" ::: "memory");
    MFMA16(af, b0, b1, 0, 1);
    __builtin_amdgcn_s_barrier();

    // phase 3: kk=1, n{2,3}; stage c3(t+1); GATE c0,c1(t+1) at end.
    b0 = *(const bf16x8*)&Bbuf[cur][4 + fs][128 + wq * 16 + fr][0];
    b1 = *(const bf16x8*)&Bbuf[cur][4 + fs][192 + wq * 16 + fr][0];
    if (pf) STAGE_CHUNK(nxt, ktn, 3);
    __builtin_amdgcn_s_barrier();
    asm volatile("s_waitcnt lgkmcnt(0)" ::: "memory");
    MFMA16(af, b0, b1, 2, 3);
    if (pf) asm volatile("s_waitcnt vmcnt(4)" ::: "memory");
    __builtin_amdgcn_s_barrier();
  }

  gemm_epilogue<EPI>(acc, smem, Cf, Cb, bias, scale, N, (long)bz * sC,
                     bm, bn, wm, wq, tid, lane);
}

// ---------------------------------------------------------------------------
// Row softmax over S [(nb)*LQ][LKK] bf16 (already scaled) -> P bf16, in-place
// capable. km/qm pointers pre-offset to the batch range.
// ---------------------------------------------------------------------------
__global__ __launch_bounds__(256)
void softmax_kernel(const bf16_t* __restrict__ S, bf16_t* __restrict__ P,
                    const float* __restrict__ km, const float* __restrict__ qm)
{
  __shared__ float red[8];
  const int r = blockIdx.x;
  const int b = r >> 11;
  const int t = threadIdx.x;
  const bf16_t* row = S + (long)r * LKK;

  const bf16x8 sv = *(const bf16x8*)(row + t * 8);
  const float4 k0 = ((const float4*)(km + (long)b * LKK))[2 * t];
  const float4 k1 = ((const float4*)(km + (long)b * LKK))[2 * t + 1];
  const float kmv[8] = {k0.x, k0.y, k0.z, k0.w, k1.x, k1.y, k1.z, k1.w};

  float v[8];
  float mx = -3.4e38f;
#pragma unroll
  for (int i = 0; i < 8; i++) {
    float s = (float)sv[i];
    s = (kmv[i] == 0.0f) ? -4294967295.0f : s;   // NEG_INF
    v[i] = s;
    mx = fmaxf(mx, s);
  }
  mx = wred_max(mx);
  if ((t & 63) == 0) red[t >> 6] = mx;
  __syncthreads();
  mx = fmaxf(fmaxf(red[0], red[1]), fmaxf(red[2], red[3]));

  float sum = 0.0f;
#pragma unroll
  for (int i = 0; i < 8; i++) {
    const float e = __expf(v[i] - mx);
    v[i] = e;
    sum += e;
  }
  sum = wred_sum(sum);
  if ((t & 63) == 0) red[4 + (t >> 6)] = sum;
  __syncthreads();
  sum = red[4] + red[5] + red[6] + red[7];

  const float rs = qm[r] / sum;
  bf16x8 o;
#pragma unroll
  for (int i = 0; i < 8; i++) o[i] = f2bf(v[i] * rs);
  *(bf16x8*)(P + (long)r * LKK + t * 8) = o;
}

// ---------------------------------------------------------------------------
// Fused residual + LayerNorm: Y = LN(X + R)*w + b  (rows of EMBD)
// MODE bit0: X bf16 (else f32); bit1: R bf16; bit2: Y bf16 (else f32).
// ---------------------------------------------------------------------------
template<int MODE>
__global__ __launch_bounds__(256)
void ln_kernel(const void* __restrict__ Xv, const void* __restrict__ Rv,
               const float* __restrict__ w, const float* __restrict__ bp,
               void* __restrict__ Yv)
{
  __shared__ float red[8];
  const long r = blockIdx.x;
  const int t = threadIdx.x;

  float x0, x1, x2, x3;
  if constexpr (MODE & 1) {
    const bf16x4 xv = ((const bf16x4*)((const bf16_t*)Xv + r * EMBD))[t];
    x0 = (float)xv[0]; x1 = (float)xv[1]; x2 = (float)xv[2]; x3 = (float)xv[3];
  } else {
    const float4 xv = ((const float4*)((const float*)Xv + r * EMBD))[t];
    x0 = xv.x; x1 = xv.y; x2 = xv.z; x3 = xv.w;
  }
  float r0, r1, r2, r3;
  if constexpr (MODE & 2) {
    const bf16x4 rv = ((const bf16x4*)((const bf16_t*)Rv + r * EMBD))[t];
    r0 = (float)rv[0]; r1 = (float)rv[1]; r2 = (float)rv[2]; r3 = (float)rv[3];
  } else {
    const float4 rv = ((const float4*)((const float*)Rv + r * EMBD))[t];
    r0 = rv.x; r1 = rv.y; r2 = rv.z; r3 = rv.w;
  }
  const float s0 = x0 + r0, s1 = x1 + r1, s2 = x2 + r2, s3 = x3 + r3;

  float sum = wred_sum(s0 + s1 + s2 + s3);
  if ((t & 63) == 0) red[t >> 6] = sum;
  __syncthreads();
  const float mu = (red[0] + red[1] + red[2] + red[3]) * (1.0f / EMBD);

  const float d0 = s0 - mu, d1 = s1 - mu, d2 = s2 - mu, d3 = s3 - mu;
  float sq = wred_sum(d0 * d0 + d1 * d1 + d2 * d2 + d3 * d3);
  if ((t & 63) == 0) red[4 + (t >> 6)] = sq;
  __syncthreads();
  const float var = (red[4] + red[5] + red[6] + red[7]) * (1.0f / EMBD);
  const float rstd = rsqrtf(var + 1e-5f);

  const float4 wv = ((const float4*)w)[t];
  const float4 bv = ((const float4*)bp)[t];
  const float y0 = d0 * rstd * wv.x + bv.x;
  const float y1 = d1 * rstd * wv.y + bv.y;
  const float y2 = d2 * rstd * wv.z + bv.z;
  const float y3 = d3 * rstd * wv.w + bv.w;

  if constexpr (MODE & 4) {
    bf16x4 o; o[0] = f2bf(y0); o[1] = f2bf(y1); o[2] = f2bf(y2); o[3] = f2bf(y3);
    ((bf16x4*)((bf16_t*)Yv + r * EMBD))[t] = o;
  } else {
    ((float4*)((float*)Yv + r * EMBD))[t] = make_float4(y0, y1, y2, y3);
  }
}

// flat f32 -> bf16 (vectorized, grid-stride)
__global__ void cvt_kernel(const float* __restrict__ in, bf16_t* __restrict__ out, long n4)
{
  long i = (long)blockIdx.x * 256 + threadIdx.x;
  const long stride = (long)gridDim.x * 256;
  for (; i < n4; i += stride) {
    const float4 v = ((const float4*)in)[i];
    bf16x4 o; o[0] = f2bf(v.x); o[1] = f2bf(v.y); o[2] = f2bf(v.z); o[3] = f2bf(v.w);
    ((bf16x4*)out)[i] = o;
  }
}

// batched [z][rows][cols] f32 -> transposed bf16 [z][cols][rows] AND straight
// bf16 copy [z][rows][cols] in one read pass.
__global__ __launch_bounds__(256)
void transpose_cvt(const float* __restrict__ in, bf16_t* __restrict__ outT,
                   bf16_t* __restrict__ outS, int rows, int cols)
{
  __shared__ bf16_t tile[32][33];
  const long zb = (long)blockIdx.z * rows * cols;
  const int cb = blockIdx.x * 32;
  const int rb = blockIdx.y * 32;
  const int tx = threadIdx.x & 31;
  const int ty = threadIdx.x >> 5;
#pragma unroll
  for (int i = 0; i < 4; i++) {
    const int rr = ty + i * 8;
    const bf16_t v = f2bf(in[zb + (long)(rb + rr) * cols + cb + tx]);
    tile[rr][tx] = v;
    if (outS != nullptr) outS[zb + (long)(rb + rr) * cols + cb + tx] = v;
  }
  __syncthreads();
#pragma unroll
  for (int i = 0; i < 4; i++) {
    const int cc = ty + i * 8;
    outT[zb + (long)(cb + cc) * rows + rb + tx] = tile[tx][cc];
  }
}

// ---------------------------------------------------------------------------
extern "C" void kernel_launch(void* const* d_in, const int* in_sizes, int n_in,
                              void* d_out, int out_size, void* d_ws, size_t ws_size,
                              hipStream_t stream)
{
  const float* q    = (const float*)d_in[0];
  const float* k    = (const float*)d_in[1];
  const float* qm   = (const float*)d_in[2];
  const float* km   = (const float*)d_in[3];
  const float* lnw  = (const float*)d_in[4];
  const float* lnb  = (const float*)d_in[5];
  const float* ln2w = (const float*)d_in[6];
  const float* ln2b = (const float*)d_in[7];
  const float* W1   = (const float*)d_in[8];
  const float* b1   = (const float*)d_in[9];
  const float* W2   = (const float*)d_in[10];
  const float* b2   = (const float*)d_in[11];

  char* ws = (char*)d_ws;
  char* ob = (char*)d_out;
  const float scale = 0.03125f;             // 1/(sqrt(1024)+1e-8)
  const long MB = 1L << 20;
  const long QE = (long)LQ * EMBD;
  const long SS = (long)LQ * LKK;

  if (ws_size >= 100 * MB) {
    // ================= Tier A: fully batched (z=8) =================
    // ws layout (lifetime-audited):
    //   [0,32)  Qb (dead after LN1) -> h
    //   [32,64) Kb (dead after QK)  -> attn/x
    //   [64,96) Kt (dead after PV)  -> y (bf16)
    //   [96,100) W1b, W2b
    // d_out: Sb (dead after PV) -> final f32 out (LN2)
    bf16_t* Qb   = (bf16_t*)ws;
    bf16_t* h    = (bf16_t*)ws;                  // overlays Qb (dead after LN1)
    bf16_t* Kb   = (bf16_t*)(ws + 32 * MB);
    bf16_t* attn = (bf16_t*)(ws + 32 * MB);      // overlays Kb (dead after QK)
    bf16_t* Kt   = (bf16_t*)(ws + 64 * MB);
    bf16_t* yb   = (bf16_t*)(ws + 64 * MB);      // overlays Kt (dead after PV)
    bf16_t* W1b  = (bf16_t*)(ws + 96 * MB);
    bf16_t* W2b  = (bf16_t*)(ws + 98 * MB);
    bf16_t* Sb   = (bf16_t*)ob;
    float*  out  = (float*)ob;

    cvt_kernel<<<1024, 256, 0, stream>>>(W1, W1b, (long)EMBD * EMBD / 4);
    cvt_kernel<<<1024, 256, 0, stream>>>(W2, W2b, (long)EMBD * EMBD / 4);
    cvt_kernel<<<4096, 256, 0, stream>>>(q, Qb, (long)NB * QE / 4);
    transpose_cvt<<<dim3(EMBD / 32, LKK / 32, NB), 256, 0, stream>>>(k, Kt, Kb, LKK, EMBD);

    // S = (Q K^T)/32
    gemm_nt8<0><<<dim3(LQ / 256, LKK / 256, NB), 512, 0, stream>>>(
        Qb, Kb, nullptr, Sb, nullptr, scale, LQ, LKK, EMBD, QE, QE, SS);
    // P = qmask * softmax(mask(S))   (in-place)
    softmax_kernel<<<NB * LQ, 256, 0, stream>>>(Sb, Sb, km, qm);
    // attn = P @ K   (into old Kb region; Kb dead)
    gemm_nt8<1><<<dim3(LQ / 256, EMBD / 256, NB), 512, 0, stream>>>(
        Sb, Kt, nullptr, attn, nullptr, 0.0f, LQ, EMBD, LKK, SS, (long)EMBD * LKK, QE);
    // x = LN(attn + Qb) in-place  (Qb bf16 residual: saves 32MB f32 read)
    ln_kernel<7><<<NB * LQ, 256, 0, stream>>>(attn, Qb, lnw, lnb, attn);
    // FFN1: h = relu(x W1^T + b1)  (into old Qb region; Qb dead after LN1)
    gemm_nt8<2><<<dim3(NB * LQ / 256, EMBD / 256, 1), 512, 0, stream>>>(
        attn, W1b, nullptr, h, b1, 0.0f, NB * LQ, EMBD, EMBD, 0, 0, 0);
    // FFN2: y = h W2^T + b2 -> bf16 (into old Kt region; saves 32MB write)
    gemm_nt8<4><<<dim3(NB * LQ / 256, EMBD / 256, 1), 512, 0, stream>>>(
        h, W2b, nullptr, yb, b2, 0.0f, NB * LQ, EMBD, EMBD, 0, 0, 0);
    // out = LN(y + x) -> f32 d_out (Sb dead; saves 32MB read)
    ln_kernel<3><<<NB * LQ, 256, 0, stream>>>(yb, attn, ln2w, ln2b, out);

  } else if (ws_size >= 52 * MB) {
    // ================= Tier B: two half-batches (z=4) =================
    bf16_t* attn = (bf16_t*)ws;
    bf16_t* W1b  = (bf16_t*)(ws + 32 * MB);
    bf16_t* W2b  = (bf16_t*)(ws + 34 * MB);
    bf16_t* Kth  = (bf16_t*)(ws + 36 * MB);
    bf16_t* h    = (bf16_t*)(ws + 36 * MB);
    bf16_t* Sb   = (bf16_t*)ob;
    bf16_t* Qbh  = (bf16_t*)(ob + 32 * MB);
    bf16_t* Kbh  = (bf16_t*)(ob + 48 * MB);
    float*  y    = (float*)ob;

    cvt_kernel<<<1024, 256, 0, stream>>>(W1, W1b, (long)EMBD * EMBD / 4);
    cvt_kernel<<<1024, 256, 0, stream>>>(W2, W2b, (long)EMBD * EMBD / 4);

    for (int it = 0; it < 2; it++) {
      const int bo = it * 4;
      const float* qh = q + bo * QE;
      const float* kh = k + bo * QE;
      cvt_kernel<<<2048, 256, 0, stream>>>(qh, Qbh, 4 * QE / 4);
      transpose_cvt<<<dim3(EMBD / 32, LKK / 32, 4), 256, 0, stream>>>(kh, Kth, Kbh, LKK, EMBD);

      gemm_nt8<0><<<dim3(LQ / 256, LKK / 256, 4), 512, 0, stream>>>(
          Qbh, Kbh, nullptr, Sb, nullptr, scale, LQ, LKK, EMBD, QE, QE, SS);
      softmax_kernel<<<4 * LQ, 256, 0, stream>>>(Sb, Sb, km + bo * LKK, qm + bo * LQ);
      gemm_nt8<1><<<dim3(LQ / 256, EMBD / 256, 4), 512, 0, stream>>>(
          Sb, Kth, nullptr, attn + bo * QE, nullptr, 0.0f, LQ, EMBD, LKK,
          SS, (long)EMBD * LKK, QE);
    }
    ln_kernel<5><<<NB * LQ, 256, 0, stream>>>(attn, q, lnw, lnb, attn);
    for (int c = 0; c < 2; c++) {
      bf16_t* xc = attn + (long)c * 8192 * EMBD;
      float*  yc = y + (long)c * 8192 * EMBD;
      gemm_nt8<2><<<dim3(8192 / 256, EMBD / 256, 1), 512, 0, stream>>>(
          xc, W1b, nullptr, h, b1, 0.0f, 8192, EMBD, EMBD, 0, 0, 0);
      gemm_nt8<3><<<dim3(8192 / 256, EMBD / 256, 1), 512, 0, stream>>>(
          h, W2b, yc, nullptr, b2, 0.0f, 8192, EMBD, EMBD, 0, 0, 0);
    }
    ln_kernel<2><<<NB * LQ, 256, 0, stream>>>(y, attn, ln2w, ln2b, y);

  } else {
    // ================= Tier C: per-batch 44 MiB fallback =================
    if (ws_size < 44 * MB) return;
    bf16_t* attn = (bf16_t*)ws;
    bf16_t* W1b  = (bf16_t*)(ws + 32 * MB);
    bf16_t* W2b  = (bf16_t*)(ws + 34 * MB);
    bf16_t* h    = (bf16_t*)(ws + 36 * MB);
    bf16_t* Sb   = (bf16_t*)(ob);
    bf16_t* Pb   = (bf16_t*)(ob + 8 * MB);
    bf16_t* Qbb  = (bf16_t*)(ob + 16 * MB);
    bf16_t* Kbb  = (bf16_t*)(ob + 20 * MB);
    bf16_t* Ktb  = (bf16_t*)(ob + 24 * MB);

    cvt_kernel<<<1024, 256, 0, stream>>>(W1, W1b, (long)EMBD * EMBD / 4);
    cvt_kernel<<<1024, 256, 0, stream>>>(W2, W2b, (long)EMBD * EMBD / 4);

    for (int b = 0; b < NB; b++) {
      const float* qb = q + b * QE;
      const float* kb = k + b * QE;
      cvt_kernel<<<2048, 256, 0, stream>>>(qb, Qbb, QE / 4);
      transpose_cvt<<<dim3(EMBD / 32, LKK / 32, 1), 256, 0, stream>>>(kb, Ktb, Kbb, LKK, EMBD);

      gemm_nt8<0><<<dim3(LQ / 256, LKK / 256, 1), 512, 0, stream>>>(
          Qbb, Kbb, nullptr, Sb, nullptr, scale, LQ, LKK, EMBD, 0, 0, 0);
      softmax_kernel<<<LQ, 256, 0, stream>>>(Sb, Pb, km + (long)b * LKK, qm + (long)b * LQ);
      gemm_nt8<1><<<dim3(LQ / 256, EMBD / 256, 1), 512, 0, stream>>>(
          Pb, Ktb, nullptr, attn + b * QE, nullptr, 0.0f, LQ, EMBD, LKK, 0, 0, 0);
    }
    ln_kernel<5><<<NB * LQ, 256, 0, stream>>>(attn, q, lnw, lnb, attn);
    for (int c = 0; c < 4; c++) {
      bf16_t* xc = attn + (long)c * 4096 * EMBD;
      float*  yc = (float*)d_out + (long)c * 4096 * EMBD;
      gemm_nt8<2><<<dim3(4096 / 256, EMBD / 256, 1), 512, 0, stream>>>(
          xc, W1b, nullptr, h, b1, 0.0f, 4096, EMBD, EMBD, 0, 0, 0);
      gemm_nt8<3><<<dim3(4096 / 256, EMBD / 256, 1), 512, 0, stream>>>(
          h, W2b, yc, nullptr, b2, 0.0f, 4096, EMBD, EMBD, 0, 0, 0);
      ln_kernel<2><<<4096, 256, 0, stream>>>(yc, xc, ln2w, ln2b, yc);
    }
  }
}